// Round 2
// baseline (922.810 us; speedup 1.0000x reference)
//
#include <hip/hip_runtime.h>
#include <hip/hip_bf16.h>

#define N_NODES 100000
#define N_EDGES 1600000
#define LATENT 64
#define N_GRAPH 100
#define OUT_G 16
#define N_STEPS 3

// ---------------- embed: x = nodes @ W_embed + b_embed ----------------
__global__ __launch_bounds__(256) void embed_kernel(
    const float* __restrict__ nodes, const float* __restrict__ We,
    const float* __restrict__ be, float* __restrict__ x)
{
    int tid = blockIdx.x * blockDim.x + threadIdx.x;
    if (tid >= N_NODES * 64) return;
    int i = tid >> 6, d = tid & 63;
    float acc = be[d];
    acc += nodes[i * 3 + 0] * We[0 * 64 + d];
    acc += nodes[i * 3 + 1] * We[1 * 64 + d];
    acc += nodes[i * 3 + 2] * We[2 * 64 + d];
    x[tid] = acc;
}

// ---------------- degree histograms ----------------
__global__ __launch_bounds__(256) void hist_kernel(
    const int* __restrict__ senders, const int* __restrict__ receivers,
    int* __restrict__ cnt_s, int* __restrict__ cnt_r)
{
    int e = blockIdx.x * blockDim.x + threadIdx.x;
    if (e >= N_EDGES) return;
    atomicAdd(&cnt_s[senders[e]], 1);
    atomicAdd(&cnt_r[receivers[e]], 1);
}

__global__ __launch_bounds__(256) void rsqrt_kernel(
    const int* __restrict__ cnt_s, const int* __restrict__ cnt_r,
    float* __restrict__ inv_s, float* __restrict__ inv_r)
{
    int i = blockIdx.x * blockDim.x + threadIdx.x;
    if (i >= N_NODES) return;
    // +1 for the self edge; degree >= 1 always so no max() needed
    inv_s[i] = rsqrtf((float)(cnt_s[i] + 1));
    inv_r[i] = rsqrtf((float)(cnt_r[i] + 1));
}

// ---------------- exclusive scan of cnt_r -> row_ptr (3 kernels) ----------------
// chunk = 1024 elements per block (256 threads x 4)
__global__ __launch_bounds__(256) void scan_blocksum(
    const int* __restrict__ cnt, int* __restrict__ partial)
{
    __shared__ int sred[256];
    int b = blockIdx.x, t = threadIdx.x;
    int base = b * 1024 + t * 4;
    int s = 0;
#pragma unroll
    for (int j = 0; j < 4; j++) {
        int i = base + j;
        s += (i < N_NODES) ? cnt[i] : 0;
    }
    sred[t] = s;
    __syncthreads();
    for (int off = 128; off > 0; off >>= 1) {
        if (t < off) sred[t] += sred[t + off];
        __syncthreads();
    }
    if (t == 0) partial[b] = sred[0];
}

__global__ void scan_partials(int* partial, int nblk)
{
    if (threadIdx.x == 0 && blockIdx.x == 0) {
        int run = 0;
        for (int b = 0; b < nblk; b++) { int v = partial[b]; partial[b] = run; run += v; }
    }
}

__global__ __launch_bounds__(256) void scan_final(
    const int* __restrict__ cnt, const int* __restrict__ partial,
    int* __restrict__ row_ptr, int* __restrict__ cursor)
{
    __shared__ int lds[256];
    int b = blockIdx.x, t = threadIdx.x;
    int base = b * 1024 + t * 4;
    int v[4]; int s = 0;
#pragma unroll
    for (int j = 0; j < 4; j++) {
        int i = base + j;
        v[j] = (i < N_NODES) ? cnt[i] : 0;
        s += v[j];
    }
    lds[t] = s;
    __syncthreads();
    // Hillis-Steele inclusive scan over 256 thread sums
    for (int off = 1; off < 256; off <<= 1) {
        int add = (t >= off) ? lds[t - off] : 0;
        __syncthreads();
        lds[t] += add;
        __syncthreads();
    }
    int run = lds[t] - s + partial[b];  // exclusive prefix for this thread
#pragma unroll
    for (int j = 0; j < 4; j++) {
        int i = base + j;
        if (i < N_NODES) {
            row_ptr[i] = run;
            cursor[i]  = run;
            run += v[j];
            if (i == N_NODES - 1) row_ptr[N_NODES] = run;
        }
    }
}

// ---------------- CSR fill (senders bucketed by receiver) ----------------
__global__ __launch_bounds__(256) void fill_csr(
    const int* __restrict__ senders, const int* __restrict__ receivers,
    int* __restrict__ cursor, int* __restrict__ col)
{
    int e = blockIdx.x * blockDim.x + threadIdx.x;
    if (e >= N_EDGES) return;
    int r = receivers[e];
    int pos = atomicAdd(&cursor[r], 1);
    col[pos] = senders[e];
}

// ---------------- fused 2-layer MLP (+ inv_sqrt_s epilogue) ----------------
__global__ __launch_bounds__(256) void mlp_kernel(
    const float* __restrict__ x, float* __restrict__ h,
    const float* __restrict__ W0, const float* __restrict__ b0,
    const float* __restrict__ W1, const float* __restrict__ b1,
    const float* __restrict__ inv_s)
{
    __shared__ float W0s[64 * 64];
    __shared__ float W1s[64 * 64];
    __shared__ float b0s[64], b1s[64];
    __shared__ float xs[4][64];
    __shared__ float ts[4][64];
    int t = threadIdx.x;
    for (int idx = t; idx < 4096; idx += 256) { W0s[idx] = W0[idx]; W1s[idx] = W1[idx]; }
    if (t < 64) { b0s[t] = b0[t]; b1s[t] = b1[t]; }
    __syncthreads();
    int w = t >> 6, lane = t & 63;
    int gw = blockIdx.x * 4 + w;
    int stride = gridDim.x * 4;
    for (int i = gw; i < N_NODES; i += stride) {
        xs[w][lane] = x[i * 64 + lane];
        float acc = b0s[lane];
#pragma unroll 16
        for (int k = 0; k < 64; k++) acc += xs[w][k] * W0s[k * 64 + lane];
        ts[w][lane] = fmaxf(acc, 0.f);
        float acc2 = b1s[lane];
#pragma unroll 16
        for (int k = 0; k < 64; k++) acc2 += ts[w][k] * W1s[k * 64 + lane];
        h[i * 64 + lane] = fmaxf(acc2, 0.f) * inv_s[i];
    }
}

// ---------------- gather-aggregate + inv_sqrt_r + skip + LayerNorm ----------------
__global__ __launch_bounds__(256) void agg_ln_kernel(
    const float* __restrict__ h, float* __restrict__ x,
    const int* __restrict__ row_ptr, const int* __restrict__ col,
    const float* __restrict__ inv_r,
    const float* __restrict__ ln_scale, const float* __restrict__ ln_bias)
{
    int t = threadIdx.x;
    int lane = t & 63;
    int gw = (blockIdx.x * blockDim.x + t) >> 6;
    int nwaves = (gridDim.x * blockDim.x) >> 6;
    for (int i = gw; i < N_NODES; i += nwaves) {
        float acc = h[i * 64 + lane];   // self edge (inv_s already folded in)
        int beg = row_ptr[i], end = row_ptr[i + 1];
        int e = beg;
        for (; e + 3 < end; e += 4) {
            int s0 = col[e], s1 = col[e + 1], s2 = col[e + 2], s3 = col[e + 3];
            float a0 = h[s0 * 64 + lane];
            float a1 = h[s1 * 64 + lane];
            float a2 = h[s2 * 64 + lane];
            float a3 = h[s3 * 64 + lane];
            acc += a0 + a1 + a2 + a3;
        }
        for (; e < end; ++e) acc += h[col[e] * 64 + lane];
        float y = acc * inv_r[i] + x[i * 64 + lane];
        // LayerNorm across 64 lanes
        float sum = y;
#pragma unroll
        for (int m = 1; m < 64; m <<= 1) sum += __shfl_xor(sum, m, 64);
        float mu = sum * (1.f / 64.f);
        float dlt = y - mu;
        float vs = dlt * dlt;
#pragma unroll
        for (int m = 1; m < 64; m <<= 1) vs += __shfl_xor(vs, m, 64);
        float var = vs * (1.f / 64.f);
        float r = rsqrtf(var + 1e-6f);
        x[i * 64 + lane] = dlt * r * ln_scale[lane] + ln_bias[lane];
    }
}

// ---------------- segment-mean pool + decoder ----------------
__global__ __launch_bounds__(256) void pool_kernel(
    const float* __restrict__ x, const int* __restrict__ n_node,
    const float* __restrict__ Wg, const float* __restrict__ bg,
    float* __restrict__ out)
{
    __shared__ float red[4][64];
    __shared__ float pd[64];
    int g = blockIdx.x;
    int t = threadIdx.x, w = t >> 6, lane = t & 63;
    int start = 0;
    for (int j = 0; j < g; j++) start += n_node[j];
    int cnt = n_node[g];
    float acc = 0.f;
    for (int j = w; j < cnt; j += 4) acc += x[(start + j) * 64 + lane];
    red[w][lane] = acc;
    __syncthreads();
    if (w == 0) {
        float s = red[0][lane] + red[1][lane] + red[2][lane] + red[3][lane];
        pd[lane] = s / fmaxf((float)cnt, 1.f);
    }
    __syncthreads();
    if (t < OUT_G) {
        float v = bg[t];
#pragma unroll 16
        for (int dd = 0; dd < 64; dd++) v += pd[dd] * Wg[dd * OUT_G + t];
        out[g * OUT_G + t] = v;
    }
}

extern "C" void kernel_launch(void* const* d_in, const int* in_sizes, int n_in,
                              void* d_out, int out_size, void* d_ws, size_t ws_size,
                              hipStream_t stream) {
    const float* nodes    = (const float*)d_in[0];
    const int*   senders  = (const int*)d_in[1];
    const int*   receivers= (const int*)d_in[2];
    const int*   n_node   = (const int*)d_in[3];
    const float* W_embed  = (const float*)d_in[4];
    const float* b_embed  = (const float*)d_in[5];
    const float* W_mlp0   = (const float*)d_in[6];
    const float* b_mlp0   = (const float*)d_in[7];
    const float* W_mlp1   = (const float*)d_in[8];
    const float* b_mlp1   = (const float*)d_in[9];
    const float* ln_scale = (const float*)d_in[10];
    const float* ln_bias  = (const float*)d_in[11];
    const float* W_glob   = (const float*)d_in[12];
    const float* b_glob   = (const float*)d_in[13];
    float* out = (float*)d_out;

    // workspace layout
    char* ws = (char*)d_ws;
    float* x      = (float*)ws;                    ws += (size_t)N_NODES * 64 * 4;
    float* h      = (float*)ws;                    ws += (size_t)N_NODES * 64 * 4;
    float* inv_s  = (float*)ws;                    ws += (size_t)N_NODES * 4;
    float* inv_r  = (float*)ws;                    ws += (size_t)N_NODES * 4;
    int*   cnt_s  = (int*)ws;                      ws += (size_t)N_NODES * 4;
    int*   cnt_r  = (int*)ws;                      ws += (size_t)N_NODES * 4;
    int*   row_ptr= (int*)ws;                      ws += (size_t)(N_NODES + 1) * 4;
    int*   cursor = (int*)ws;                      ws += (size_t)N_NODES * 4;
    int*   col    = (int*)ws;                      ws += (size_t)N_EDGES * 4;
    int*   partial= (int*)ws;                      ws += 256 * 4;

    const int nblk_scan = (N_NODES + 1023) / 1024;  // 98

    // zero the two histograms (contiguous)
    hipMemsetAsync(cnt_s, 0, 2 * (size_t)N_NODES * 4, stream);

    embed_kernel<<<(N_NODES * 64 + 255) / 256, 256, 0, stream>>>(nodes, W_embed, b_embed, x);
    hist_kernel<<<(N_EDGES + 255) / 256, 256, 0, stream>>>(senders, receivers, cnt_s, cnt_r);
    rsqrt_kernel<<<(N_NODES + 255) / 256, 256, 0, stream>>>(cnt_s, cnt_r, inv_s, inv_r);
    scan_blocksum<<<nblk_scan, 256, 0, stream>>>(cnt_r, partial);
    scan_partials<<<1, 64, 0, stream>>>(partial, nblk_scan);
    scan_final<<<nblk_scan, 256, 0, stream>>>(cnt_r, partial, row_ptr, cursor);
    fill_csr<<<(N_EDGES + 255) / 256, 256, 0, stream>>>(senders, receivers, cursor, col);

    for (int step = 0; step < N_STEPS; ++step) {
        mlp_kernel<<<512, 256, 0, stream>>>(x, h, W_mlp0, b_mlp0, W_mlp1, b_mlp1, inv_s);
        agg_ln_kernel<<<2048, 256, 0, stream>>>(h, x, row_ptr, col, inv_r, ln_scale, ln_bias);
    }

    pool_kernel<<<N_GRAPH, 256, 0, stream>>>(x, n_node, W_glob, b_glob, out);
}

// Round 3
// 662.114 us; speedup vs baseline: 1.3937x; 1.3937x over previous
//
#include <hip/hip_runtime.h>
#include <hip/hip_bf16.h>

#define N_NODES 100000
#define N_EDGES 1600000
#define LATENT 64
#define N_GRAPH 100
#define OUT_G 16
#define N_STEPS 3

using bf16 = __hip_bfloat16;
using bf16x8 = __attribute__((ext_vector_type(8))) short;
using f32x4  = __attribute__((ext_vector_type(4))) float;

// ---------------- embed: x = nodes @ W_embed + b_embed (f32 + bf16 shadow) ----
__global__ __launch_bounds__(256) void embed_kernel(
    const float* __restrict__ nodes, const float* __restrict__ We,
    const float* __restrict__ be, float* __restrict__ x, bf16* __restrict__ xb)
{
    int tid = blockIdx.x * blockDim.x + threadIdx.x;
    if (tid >= N_NODES * 64) return;
    int i = tid >> 6, d = tid & 63;
    float acc = be[d];
    acc += nodes[i * 3 + 0] * We[0 * 64 + d];
    acc += nodes[i * 3 + 1] * We[1 * 64 + d];
    acc += nodes[i * 3 + 2] * We[2 * 64 + d];
    x[tid] = acc;
    xb[tid] = __float2bfloat16(acc);
}

// ---------------- degree histograms ----------------
__global__ __launch_bounds__(256) void hist_kernel(
    const int* __restrict__ senders, const int* __restrict__ receivers,
    int* __restrict__ cnt_s, int* __restrict__ cnt_r)
{
    int e = blockIdx.x * blockDim.x + threadIdx.x;
    if (e >= N_EDGES) return;
    atomicAdd(&cnt_s[senders[e]], 1);
    atomicAdd(&cnt_r[receivers[e]], 1);
}

__global__ __launch_bounds__(256) void rsqrt_kernel(
    const int* __restrict__ cnt_s, const int* __restrict__ cnt_r,
    float* __restrict__ inv_s, float* __restrict__ inv_r)
{
    int i = blockIdx.x * blockDim.x + threadIdx.x;
    if (i >= N_NODES) return;
    inv_s[i] = rsqrtf((float)(cnt_s[i] + 1));
    inv_r[i] = rsqrtf((float)(cnt_r[i] + 1));
}

// ---------------- exclusive scan of cnt_r -> row_ptr ----------------
__global__ __launch_bounds__(256) void scan_blocksum(
    const int* __restrict__ cnt, int* __restrict__ partial)
{
    __shared__ int sred[256];
    int b = blockIdx.x, t = threadIdx.x;
    int base = b * 1024 + t * 4;
    int s = 0;
#pragma unroll
    for (int j = 0; j < 4; j++) {
        int i = base + j;
        s += (i < N_NODES) ? cnt[i] : 0;
    }
    sred[t] = s;
    __syncthreads();
    for (int off = 128; off > 0; off >>= 1) {
        if (t < off) sred[t] += sred[t + off];
        __syncthreads();
    }
    if (t == 0) partial[b] = sred[0];
}

__global__ void scan_partials(int* partial, int nblk)
{
    if (threadIdx.x == 0 && blockIdx.x == 0) {
        int run = 0;
        for (int b = 0; b < nblk; b++) { int v = partial[b]; partial[b] = run; run += v; }
    }
}

__global__ __launch_bounds__(256) void scan_final(
    const int* __restrict__ cnt, const int* __restrict__ partial,
    int* __restrict__ row_ptr, int* __restrict__ cursor)
{
    __shared__ int lds[256];
    int b = blockIdx.x, t = threadIdx.x;
    int base = b * 1024 + t * 4;
    int v[4]; int s = 0;
#pragma unroll
    for (int j = 0; j < 4; j++) {
        int i = base + j;
        v[j] = (i < N_NODES) ? cnt[i] : 0;
        s += v[j];
    }
    lds[t] = s;
    __syncthreads();
    for (int off = 1; off < 256; off <<= 1) {
        int add = (t >= off) ? lds[t - off] : 0;
        __syncthreads();
        lds[t] += add;
        __syncthreads();
    }
    int run = lds[t] - s + partial[b];
#pragma unroll
    for (int j = 0; j < 4; j++) {
        int i = base + j;
        if (i < N_NODES) {
            row_ptr[i] = run;
            cursor[i]  = run;
            run += v[j];
            if (i == N_NODES - 1) row_ptr[N_NODES] = run;
        }
    }
}

// ---------------- CSR fill ----------------
__global__ __launch_bounds__(256) void fill_csr(
    const int* __restrict__ senders, const int* __restrict__ receivers,
    int* __restrict__ cursor, int* __restrict__ col)
{
    int e = blockIdx.x * blockDim.x + threadIdx.x;
    if (e >= N_EDGES) return;
    int r = receivers[e];
    int pos = atomicAdd(&cursor[r], 1);
    col[pos] = senders[e];
}

// ---------------- W fragment pre-pack (f32 -> bf16, MFMA frag order) ----------
// layout: idx = (((L*4+nt)*2+c)*64 + lane)*8 + j ; value = W_L[c*32+g*8+j][nt*16+q]
__global__ __launch_bounds__(256) void wfrag_kernel(
    const float* __restrict__ W0, const float* __restrict__ W1,
    bf16* __restrict__ frags)
{
    int tid = blockIdx.x * blockDim.x + threadIdx.x;
    if (tid >= 8192) return;
    int j    = tid & 7;
    int lane = (tid >> 3) & 63;
    int c    = (tid >> 9) & 1;
    int nt   = (tid >> 10) & 3;
    int L    = (tid >> 12) & 1;
    int g = lane >> 4, q = lane & 15;
    int k = c * 32 + g * 8 + j;
    int colIdx = nt * 16 + q;
    const float* W = L ? W1 : W0;
    frags[tid] = __float2bfloat16(W[k * 64 + colIdx]);
}

// ---------------- MFMA 2-layer MLP (+ inv_sqrt_s epilogue), bf16 ----------------
// one wave processes 16 consecutive nodes; 6250 tiles total
__global__ __launch_bounds__(256) void mlp_mfma(
    const bf16* __restrict__ xb, bf16* __restrict__ h,
    const bf16* __restrict__ wfrag,
    const float* __restrict__ b0, const float* __restrict__ b1,
    const float* __restrict__ inv_s)
{
    __shared__ char lds_raw[4][2048];
    int t = threadIdx.x;
    int w = t >> 6, lane = t & 63;
    int g = lane >> 4, q = lane & 15;
    char* myLds = lds_raw[w];

    // load all W fragments (16 x 16B per lane, coalesced)
    bf16x8 wf[2][4][2];
#pragma unroll
    for (int L = 0; L < 2; L++)
#pragma unroll
        for (int nt = 0; nt < 4; nt++)
#pragma unroll
            for (int c = 0; c < 2; c++)
                wf[L][nt][c] = *(const bf16x8*)&wfrag[((((L * 4 + nt) * 2 + c) * 64) + lane) * 8];

    float bias0[4], bias1[4];
#pragma unroll
    for (int nt = 0; nt < 4; nt++) {
        bias0[nt] = b0[nt * 16 + q];
        bias1[nt] = b1[nt * 16 + q];
    }

    const int NTILES = N_NODES / 16;  // 6250
    for (int tile = blockIdx.x * 4 + w; tile < NTILES; tile += gridDim.x * 4) {
        int nodeBase = tile * 16;

        // A fragments from global x_bf16 (node = q, k = c*32+g*8+j)
        bf16x8 a0[2];
#pragma unroll
        for (int c = 0; c < 2; c++)
            a0[c] = *(const bf16x8*)&xb[(size_t)(nodeBase + q) * 64 + c * 32 + g * 8];

        // ---- layer 0 ----
        f32x4 acc[4];
#pragma unroll
        for (int nt = 0; nt < 4; nt++) {
            acc[nt] = (f32x4){bias0[nt], bias0[nt], bias0[nt], bias0[nt]};
            acc[nt] = __builtin_amdgcn_mfma_f32_16x16x32_bf16(a0[0], wf[0][nt][0], acc[nt], 0, 0, 0);
            acc[nt] = __builtin_amdgcn_mfma_f32_16x16x32_bf16(a0[1], wf[0][nt][1], acc[nt], 0, 0, 0);
        }
        // relu -> bf16 -> swizzled LDS (C layout: node=g*4+r, col=nt*16+q)
#pragma unroll
        for (int nt = 0; nt < 4; nt++)
#pragma unroll
            for (int r = 0; r < 4; r++) {
                float v = fmaxf(acc[nt][r], 0.f);
                int node = g * 4 + r;
                int byte = ((node * 128 + (nt * 16 + q) * 2)) ^ ((node & 7) << 4);
                *(bf16*)(myLds + byte) = __float2bfloat16(v);
            }
        // layer-1 A frags from LDS (node = q, k = c*32+g*8+j)
        bf16x8 a1[2];
#pragma unroll
        for (int c = 0; c < 2; c++) {
            int byte = (q * 128 + c * 64 + g * 16) ^ ((q & 7) << 4);
            a1[c] = *(const bf16x8*)(myLds + byte);
        }

        // ---- layer 1 ----
        f32x4 acc1[4];
#pragma unroll
        for (int nt = 0; nt < 4; nt++) {
            acc1[nt] = (f32x4){bias1[nt], bias1[nt], bias1[nt], bias1[nt]};
            acc1[nt] = __builtin_amdgcn_mfma_f32_16x16x32_bf16(a1[0], wf[1][nt][0], acc1[nt], 0, 0, 0);
            acc1[nt] = __builtin_amdgcn_mfma_f32_16x16x32_bf16(a1[1], wf[1][nt][1], acc1[nt], 0, 0, 0);
        }
        float is[4];
#pragma unroll
        for (int r = 0; r < 4; r++) is[r] = inv_s[nodeBase + g * 4 + r];
#pragma unroll
        for (int nt = 0; nt < 4; nt++)
#pragma unroll
            for (int r = 0; r < 4; r++) {
                float v = fmaxf(acc1[nt][r], 0.f) * is[r];
                int node = g * 4 + r;
                int byte = ((node * 128 + (nt * 16 + q) * 2)) ^ ((node & 7) << 4);
                *(bf16*)(myLds + byte) = __float2bfloat16(v);
            }
        // linear read-back + coalesced global store (2 x 16B per lane)
#pragma unroll
        for (int half = 0; half < 2; half++) {
            int byteL = lane * 32 + half * 16;
            int node = byteL >> 7;
            bf16x8 v = *(const bf16x8*)(myLds + (byteL ^ ((node & 7) << 4)));
            *(bf16x8*)&h[(size_t)nodeBase * 64 + lane * 16 + half * 8] = v;
        }
    }
}

// ---------------- gather-aggregate (bf16 h) + inv_sqrt_r + skip + LayerNorm ----
__global__ __launch_bounds__(256) void agg_ln_kernel(
    const bf16* __restrict__ h, float* __restrict__ x, bf16* __restrict__ xb,
    const int* __restrict__ row_ptr, const int* __restrict__ col,
    const float* __restrict__ inv_r,
    const float* __restrict__ ln_scale, const float* __restrict__ ln_bias)
{
    int t = threadIdx.x;
    int lane = t & 63;
    int gw = (blockIdx.x * blockDim.x + t) >> 6;
    int nwaves = (gridDim.x * blockDim.x) >> 6;
    for (int i = gw; i < N_NODES; i += nwaves) {
        float acc = __bfloat162float(h[(size_t)i * 64 + lane]);  // self edge
        int beg = row_ptr[i], end = row_ptr[i + 1];
        int e = beg;
        for (; e + 3 < end; e += 4) {
            int s0 = col[e], s1 = col[e + 1], s2 = col[e + 2], s3 = col[e + 3];
            float a0 = __bfloat162float(h[(size_t)s0 * 64 + lane]);
            float a1 = __bfloat162float(h[(size_t)s1 * 64 + lane]);
            float a2 = __bfloat162float(h[(size_t)s2 * 64 + lane]);
            float a3 = __bfloat162float(h[(size_t)s3 * 64 + lane]);
            acc += a0 + a1 + a2 + a3;
        }
        for (; e < end; ++e) acc += __bfloat162float(h[(size_t)col[e] * 64 + lane]);
        float y = acc * inv_r[i] + x[(size_t)i * 64 + lane];
        float sum = y;
#pragma unroll
        for (int m = 1; m < 64; m <<= 1) sum += __shfl_xor(sum, m, 64);
        float mu = sum * (1.f / 64.f);
        float dlt = y - mu;
        float vs = dlt * dlt;
#pragma unroll
        for (int m = 1; m < 64; m <<= 1) vs += __shfl_xor(vs, m, 64);
        float var = vs * (1.f / 64.f);
        float r = rsqrtf(var + 1e-6f);
        float outv = dlt * r * ln_scale[lane] + ln_bias[lane];
        x[(size_t)i * 64 + lane] = outv;
        xb[(size_t)i * 64 + lane] = __float2bfloat16(outv);
    }
}

// ---------------- segment-mean pool + decoder ----------------
__global__ __launch_bounds__(256) void pool_kernel(
    const float* __restrict__ x, const int* __restrict__ n_node,
    const float* __restrict__ Wg, const float* __restrict__ bg,
    float* __restrict__ out)
{
    __shared__ float red[4][64];
    __shared__ float pd[64];
    int g = blockIdx.x;
    int t = threadIdx.x, w = t >> 6, lane = t & 63;
    int start = 0;
    for (int j = 0; j < g; j++) start += n_node[j];
    int cnt = n_node[g];
    float acc = 0.f;
    for (int j = w; j < cnt; j += 4) acc += x[(size_t)(start + j) * 64 + lane];
    red[w][lane] = acc;
    __syncthreads();
    if (w == 0) {
        float s = red[0][lane] + red[1][lane] + red[2][lane] + red[3][lane];
        pd[lane] = s / fmaxf((float)cnt, 1.f);
    }
    __syncthreads();
    if (t < OUT_G) {
        float v = bg[t];
#pragma unroll 16
        for (int dd = 0; dd < 64; dd++) v += pd[dd] * Wg[dd * OUT_G + t];
        out[g * OUT_G + t] = v;
    }
}

extern "C" void kernel_launch(void* const* d_in, const int* in_sizes, int n_in,
                              void* d_out, int out_size, void* d_ws, size_t ws_size,
                              hipStream_t stream) {
    const float* nodes    = (const float*)d_in[0];
    const int*   senders  = (const int*)d_in[1];
    const int*   receivers= (const int*)d_in[2];
    const int*   n_node   = (const int*)d_in[3];
    const float* W_embed  = (const float*)d_in[4];
    const float* b_embed  = (const float*)d_in[5];
    const float* W_mlp0   = (const float*)d_in[6];
    const float* b_mlp0   = (const float*)d_in[7];
    const float* W_mlp1   = (const float*)d_in[8];
    const float* b_mlp1   = (const float*)d_in[9];
    const float* ln_scale = (const float*)d_in[10];
    const float* ln_bias  = (const float*)d_in[11];
    const float* W_glob   = (const float*)d_in[12];
    const float* b_glob   = (const float*)d_in[13];
    float* out = (float*)d_out;

    // workspace layout (16B-aligned pieces)
    char* ws = (char*)d_ws;
    float* x      = (float*)ws;   ws += (size_t)N_NODES * 64 * 4;   // 25.6 MB
    bf16*  xb     = (bf16*)ws;    ws += (size_t)N_NODES * 64 * 2;   // 12.8 MB
    bf16*  h      = (bf16*)ws;    ws += (size_t)N_NODES * 64 * 2;   // 12.8 MB
    float* inv_s  = (float*)ws;   ws += (size_t)N_NODES * 4;
    float* inv_r  = (float*)ws;   ws += (size_t)N_NODES * 4;
    int*   cnt_s  = (int*)ws;     ws += (size_t)N_NODES * 4;
    int*   cnt_r  = (int*)ws;     ws += (size_t)N_NODES * 4;
    int*   row_ptr= (int*)ws;     ws += (size_t)(N_NODES + 4) * 4;
    int*   cursor = (int*)ws;     ws += (size_t)N_NODES * 4;
    int*   col    = (int*)ws;     ws += (size_t)N_EDGES * 4;
    int*   partial= (int*)ws;     ws += 256 * 4;
    bf16*  wfrag  = (bf16*)ws;    ws += 8192 * 2;

    const int nblk_scan = (N_NODES + 1023) / 1024;  // 98

    hipMemsetAsync(cnt_s, 0, 2 * (size_t)N_NODES * 4, stream);

    embed_kernel<<<(N_NODES * 64 + 255) / 256, 256, 0, stream>>>(nodes, W_embed, b_embed, x, xb);
    hist_kernel<<<(N_EDGES + 255) / 256, 256, 0, stream>>>(senders, receivers, cnt_s, cnt_r);
    rsqrt_kernel<<<(N_NODES + 255) / 256, 256, 0, stream>>>(cnt_s, cnt_r, inv_s, inv_r);
    scan_blocksum<<<nblk_scan, 256, 0, stream>>>(cnt_r, partial);
    scan_partials<<<1, 64, 0, stream>>>(partial, nblk_scan);
    scan_final<<<nblk_scan, 256, 0, stream>>>(cnt_r, partial, row_ptr, cursor);
    fill_csr<<<(N_EDGES + 255) / 256, 256, 0, stream>>>(senders, receivers, cursor, col);
    wfrag_kernel<<<32, 256, 0, stream>>>(W_mlp0, W_mlp1, wfrag);

    for (int step = 0; step < N_STEPS; ++step) {
        mlp_mfma<<<1024, 256, 0, stream>>>(xb, h, wfrag, b_mlp0, b_mlp1, inv_s);
        agg_ln_kernel<<<2048, 256, 0, stream>>>(h, x, xb, row_ptr, col, inv_r, ln_scale, ln_bias);
    }

    pool_kernel<<<N_GRAPH, 256, 0, stream>>>(x, n_node, W_glob, b_glob, out);
}

// Round 4
// 599.044 us; speedup vs baseline: 1.5405x; 1.1053x over previous
//
#include <hip/hip_runtime.h>
#include <hip/hip_bf16.h>

#define N_NODES 100000
#define N_EDGES 1600000
#define LATENT 64
#define N_GRAPH 100
#define OUT_G 16
#define N_STEPS 3

using bf16 = __hip_bfloat16;
using bf16x8 = __attribute__((ext_vector_type(8))) short;
using f32x4  = __attribute__((ext_vector_type(4))) float;

// ---------------- embed: x = nodes @ W_embed + b_embed (f32 + bf16 shadow) ----
__global__ __launch_bounds__(256) void embed_kernel(
    const float* __restrict__ nodes, const float* __restrict__ We,
    const float* __restrict__ be, float* __restrict__ x, bf16* __restrict__ xb)
{
    int tid = blockIdx.x * blockDim.x + threadIdx.x;
    if (tid >= N_NODES * 64) return;
    int i = tid >> 6, d = tid & 63;
    float acc = be[d];
    acc += nodes[i * 3 + 0] * We[0 * 64 + d];
    acc += nodes[i * 3 + 1] * We[1 * 64 + d];
    acc += nodes[i * 3 + 2] * We[2 * 64 + d];
    x[tid] = acc;
    xb[tid] = __float2bfloat16(acc);
}

// ---------------- pass 1: degree histograms + within-receiver rank ----------------
// the cnt_r atomic doubles as rank capture; fill needs no atomics afterwards
__global__ __launch_bounds__(256) void edge_rank_kernel(
    const int* __restrict__ senders, const int* __restrict__ receivers,
    int* __restrict__ cnt_s, int* __restrict__ cnt_r, int* __restrict__ rank)
{
    int e = blockIdx.x * blockDim.x + threadIdx.x;
    if (e >= N_EDGES) return;
    atomicAdd(&cnt_s[senders[e]], 1);
    rank[e] = atomicAdd(&cnt_r[receivers[e]], 1);
}

__global__ __launch_bounds__(256) void rsqrt_kernel(
    const int* __restrict__ cnt_s, const int* __restrict__ cnt_r,
    float* __restrict__ inv_s, float* __restrict__ inv_r)
{
    int i = blockIdx.x * blockDim.x + threadIdx.x;
    if (i >= N_NODES) return;
    inv_s[i] = rsqrtf((float)(cnt_s[i] + 1));
    inv_r[i] = rsqrtf((float)(cnt_r[i] + 1));
}

// ---------------- exclusive scan of cnt_r -> row_ptr ----------------
__global__ __launch_bounds__(256) void scan_blocksum(
    const int* __restrict__ cnt, int* __restrict__ partial)
{
    __shared__ int sred[256];
    int b = blockIdx.x, t = threadIdx.x;
    int base = b * 1024 + t * 4;
    int s = 0;
#pragma unroll
    for (int j = 0; j < 4; j++) {
        int i = base + j;
        s += (i < N_NODES) ? cnt[i] : 0;
    }
    sred[t] = s;
    __syncthreads();
    for (int off = 128; off > 0; off >>= 1) {
        if (t < off) sred[t] += sred[t + off];
        __syncthreads();
    }
    if (t == 0) partial[b] = sred[0];
}

__global__ void scan_partials(int* partial, int nblk)
{
    if (threadIdx.x == 0 && blockIdx.x == 0) {
        int run = 0;
        for (int b = 0; b < nblk; b++) { int v = partial[b]; partial[b] = run; run += v; }
    }
}

__global__ __launch_bounds__(256) void scan_final(
    const int* __restrict__ cnt, const int* __restrict__ partial,
    int* __restrict__ row_ptr)
{
    __shared__ int lds[256];
    int b = blockIdx.x, t = threadIdx.x;
    int base = b * 1024 + t * 4;
    int v[4]; int s = 0;
#pragma unroll
    for (int j = 0; j < 4; j++) {
        int i = base + j;
        v[j] = (i < N_NODES) ? cnt[i] : 0;
        s += v[j];
    }
    lds[t] = s;
    __syncthreads();
    for (int off = 1; off < 256; off <<= 1) {
        int add = (t >= off) ? lds[t - off] : 0;
        __syncthreads();
        lds[t] += add;
        __syncthreads();
    }
    int run = lds[t] - s + partial[b];
#pragma unroll
    for (int j = 0; j < 4; j++) {
        int i = base + j;
        if (i < N_NODES) {
            row_ptr[i] = run;
            run += v[j];
            if (i == N_NODES - 1) row_ptr[N_NODES] = run;
        }
    }
}

// ---------------- pass 2: CSR scatter, no atomics ----------------
__global__ __launch_bounds__(256) void scatter_csr(
    const int* __restrict__ senders, const int* __restrict__ receivers,
    const int* __restrict__ row_ptr, const int* __restrict__ rank,
    int* __restrict__ col)
{
    int e = blockIdx.x * blockDim.x + threadIdx.x;
    if (e >= N_EDGES) return;
    col[row_ptr[receivers[e]] + rank[e]] = senders[e];
}

// ---------------- W fragment pre-pack (f32 -> bf16, MFMA frag order) ----------
__global__ __launch_bounds__(256) void wfrag_kernel(
    const float* __restrict__ W0, const float* __restrict__ W1,
    bf16* __restrict__ frags)
{
    int tid = blockIdx.x * blockDim.x + threadIdx.x;
    if (tid >= 8192) return;
    int j    = tid & 7;
    int lane = (tid >> 3) & 63;
    int c    = (tid >> 9) & 1;
    int nt   = (tid >> 10) & 3;
    int L    = (tid >> 12) & 1;
    int g = lane >> 4, q = lane & 15;
    int k = c * 32 + g * 8 + j;
    int colIdx = nt * 16 + q;
    const float* W = L ? W1 : W0;
    frags[tid] = __float2bfloat16(W[k * 64 + colIdx]);
}

// ---------------- MFMA 2-layer MLP (+ inv_sqrt_s epilogue), bf16 ----------------
__global__ __launch_bounds__(256) void mlp_mfma(
    const bf16* __restrict__ xb, bf16* __restrict__ h,
    const bf16* __restrict__ wfrag,
    const float* __restrict__ b0, const float* __restrict__ b1,
    const float* __restrict__ inv_s)
{
    __shared__ char lds_raw[4][2048];
    int t = threadIdx.x;
    int w = t >> 6, lane = t & 63;
    int g = lane >> 4, q = lane & 15;
    char* myLds = lds_raw[w];

    bf16x8 wf[2][4][2];
#pragma unroll
    for (int L = 0; L < 2; L++)
#pragma unroll
        for (int nt = 0; nt < 4; nt++)
#pragma unroll
            for (int c = 0; c < 2; c++)
                wf[L][nt][c] = *(const bf16x8*)&wfrag[((((L * 4 + nt) * 2 + c) * 64) + lane) * 8];

    float bias0[4], bias1[4];
#pragma unroll
    for (int nt = 0; nt < 4; nt++) {
        bias0[nt] = b0[nt * 16 + q];
        bias1[nt] = b1[nt * 16 + q];
    }

    const int NTILES = N_NODES / 16;  // 6250
    for (int tile = blockIdx.x * 4 + w; tile < NTILES; tile += gridDim.x * 4) {
        int nodeBase = tile * 16;

        bf16x8 a0[2];
#pragma unroll
        for (int c = 0; c < 2; c++)
            a0[c] = *(const bf16x8*)&xb[(size_t)(nodeBase + q) * 64 + c * 32 + g * 8];

        f32x4 acc[4];
#pragma unroll
        for (int nt = 0; nt < 4; nt++) {
            acc[nt] = (f32x4){bias0[nt], bias0[nt], bias0[nt], bias0[nt]};
            acc[nt] = __builtin_amdgcn_mfma_f32_16x16x32_bf16(a0[0], wf[0][nt][0], acc[nt], 0, 0, 0);
            acc[nt] = __builtin_amdgcn_mfma_f32_16x16x32_bf16(a0[1], wf[0][nt][1], acc[nt], 0, 0, 0);
        }
#pragma unroll
        for (int nt = 0; nt < 4; nt++)
#pragma unroll
            for (int r = 0; r < 4; r++) {
                float v = fmaxf(acc[nt][r], 0.f);
                int node = g * 4 + r;
                int byte = ((node * 128 + (nt * 16 + q) * 2)) ^ ((node & 7) << 4);
                *(bf16*)(myLds + byte) = __float2bfloat16(v);
            }
        bf16x8 a1[2];
#pragma unroll
        for (int c = 0; c < 2; c++) {
            int byte = (q * 128 + c * 64 + g * 16) ^ ((q & 7) << 4);
            a1[c] = *(const bf16x8*)(myLds + byte);
        }

        f32x4 acc1[4];
#pragma unroll
        for (int nt = 0; nt < 4; nt++) {
            acc1[nt] = (f32x4){bias1[nt], bias1[nt], bias1[nt], bias1[nt]};
            acc1[nt] = __builtin_amdgcn_mfma_f32_16x16x32_bf16(a1[0], wf[1][nt][0], acc1[nt], 0, 0, 0);
            acc1[nt] = __builtin_amdgcn_mfma_f32_16x16x32_bf16(a1[1], wf[1][nt][1], acc1[nt], 0, 0, 0);
        }
        float is[4];
#pragma unroll
        for (int r = 0; r < 4; r++) is[r] = inv_s[nodeBase + g * 4 + r];
#pragma unroll
        for (int nt = 0; nt < 4; nt++)
#pragma unroll
            for (int r = 0; r < 4; r++) {
                float v = fmaxf(acc1[nt][r], 0.f) * is[r];
                int node = g * 4 + r;
                int byte = ((node * 128 + (nt * 16 + q) * 2)) ^ ((node & 7) << 4);
                *(bf16*)(myLds + byte) = __float2bfloat16(v);
            }
#pragma unroll
        for (int half = 0; half < 2; half++) {
            int byteL = lane * 32 + half * 16;
            int node = byteL >> 7;
            bf16x8 v = *(const bf16x8*)(myLds + (byteL ^ ((node & 7) << 4)));
            *(bf16x8*)&h[(size_t)nodeBase * 64 + lane * 16 + half * 8] = v;
        }
    }
}

// ---------------- gather-aggregate (bf16 h) + inv_sqrt_r + skip + LayerNorm ----
__global__ __launch_bounds__(256) void agg_ln_kernel(
    const bf16* __restrict__ h, float* __restrict__ x, bf16* __restrict__ xb,
    const int* __restrict__ row_ptr, const int* __restrict__ col,
    const float* __restrict__ inv_r,
    const float* __restrict__ ln_scale, const float* __restrict__ ln_bias)
{
    int t = threadIdx.x;
    int lane = t & 63;
    float lns = ln_scale[lane], lnb = ln_bias[lane];
    int gw = (blockIdx.x * blockDim.x + t) >> 6;
    int nwaves = (gridDim.x * blockDim.x) >> 6;
    for (int i = gw; i < N_NODES; i += nwaves) {
        float acc = __bfloat162float(h[(size_t)i * 64 + lane]);  // self edge
        float acc2 = 0.f;
        int beg = row_ptr[i], end = row_ptr[i + 1];
        int e = beg;
        for (; e + 7 < end; e += 8) {
            int s0 = col[e],     s1 = col[e + 1], s2 = col[e + 2], s3 = col[e + 3];
            int s4 = col[e + 4], s5 = col[e + 5], s6 = col[e + 6], s7 = col[e + 7];
            float a0 = __bfloat162float(h[(size_t)s0 * 64 + lane]);
            float a1 = __bfloat162float(h[(size_t)s1 * 64 + lane]);
            float a2 = __bfloat162float(h[(size_t)s2 * 64 + lane]);
            float a3 = __bfloat162float(h[(size_t)s3 * 64 + lane]);
            float a4 = __bfloat162float(h[(size_t)s4 * 64 + lane]);
            float a5 = __bfloat162float(h[(size_t)s5 * 64 + lane]);
            float a6 = __bfloat162float(h[(size_t)s6 * 64 + lane]);
            float a7 = __bfloat162float(h[(size_t)s7 * 64 + lane]);
            acc  += (a0 + a1) + (a2 + a3);
            acc2 += (a4 + a5) + (a6 + a7);
        }
        for (; e < end; ++e) acc += __bfloat162float(h[(size_t)col[e] * 64 + lane]);
        float y = (acc + acc2) * inv_r[i] + x[(size_t)i * 64 + lane];
        float sum = y;
#pragma unroll
        for (int m = 1; m < 64; m <<= 1) sum += __shfl_xor(sum, m, 64);
        float mu = sum * (1.f / 64.f);
        float dlt = y - mu;
        float vs = dlt * dlt;
#pragma unroll
        for (int m = 1; m < 64; m <<= 1) vs += __shfl_xor(vs, m, 64);
        float var = vs * (1.f / 64.f);
        float r = rsqrtf(var + 1e-6f);
        float outv = dlt * r * lns + lnb;
        x[(size_t)i * 64 + lane] = outv;
        xb[(size_t)i * 64 + lane] = __float2bfloat16(outv);
    }
}

// ---------------- segment-mean pool + decoder ----------------
__global__ __launch_bounds__(256) void pool_kernel(
    const float* __restrict__ x, const int* __restrict__ n_node,
    const float* __restrict__ Wg, const float* __restrict__ bg,
    float* __restrict__ out)
{
    __shared__ float red[4][64];
    __shared__ float pd[64];
    int g = blockIdx.x;
    int t = threadIdx.x, w = t >> 6, lane = t & 63;
    int start = 0;
    for (int j = 0; j < g; j++) start += n_node[j];
    int cnt = n_node[g];
    float acc = 0.f;
    for (int j = w; j < cnt; j += 4) acc += x[(size_t)(start + j) * 64 + lane];
    red[w][lane] = acc;
    __syncthreads();
    if (w == 0) {
        float s = red[0][lane] + red[1][lane] + red[2][lane] + red[3][lane];
        pd[lane] = s / fmaxf((float)cnt, 1.f);
    }
    __syncthreads();
    if (t < OUT_G) {
        float v = bg[t];
#pragma unroll 16
        for (int dd = 0; dd < 64; dd++) v += pd[dd] * Wg[dd * OUT_G + t];
        out[g * OUT_G + t] = v;
    }
}

extern "C" void kernel_launch(void* const* d_in, const int* in_sizes, int n_in,
                              void* d_out, int out_size, void* d_ws, size_t ws_size,
                              hipStream_t stream) {
    const float* nodes    = (const float*)d_in[0];
    const int*   senders  = (const int*)d_in[1];
    const int*   receivers= (const int*)d_in[2];
    const int*   n_node   = (const int*)d_in[3];
    const float* W_embed  = (const float*)d_in[4];
    const float* b_embed  = (const float*)d_in[5];
    const float* W_mlp0   = (const float*)d_in[6];
    const float* b_mlp0   = (const float*)d_in[7];
    const float* W_mlp1   = (const float*)d_in[8];
    const float* b_mlp1   = (const float*)d_in[9];
    const float* ln_scale = (const float*)d_in[10];
    const float* ln_bias  = (const float*)d_in[11];
    const float* W_glob   = (const float*)d_in[12];
    const float* b_glob   = (const float*)d_in[13];
    float* out = (float*)d_out;

    // workspace layout (16B-aligned pieces)
    char* ws = (char*)d_ws;
    float* x      = (float*)ws;   ws += (size_t)N_NODES * 64 * 4;   // 25.6 MB
    bf16*  xb     = (bf16*)ws;    ws += (size_t)N_NODES * 64 * 2;   // 12.8 MB
    bf16*  h      = (bf16*)ws;    ws += (size_t)N_NODES * 64 * 2;   // 12.8 MB
    float* inv_s  = (float*)ws;   ws += (size_t)N_NODES * 4;
    float* inv_r  = (float*)ws;   ws += (size_t)N_NODES * 4;
    int*   cnt_s  = (int*)ws;     ws += (size_t)N_NODES * 4;
    int*   cnt_r  = (int*)ws;     ws += (size_t)N_NODES * 4;
    int*   row_ptr= (int*)ws;     ws += (size_t)(N_NODES + 4) * 4;
    int*   col    = (int*)ws;     ws += (size_t)N_EDGES * 4;
    int*   rank   = (int*)ws;     ws += (size_t)N_EDGES * 4;
    int*   partial= (int*)ws;     ws += 256 * 4;
    bf16*  wfrag  = (bf16*)ws;    ws += 8192 * 2;

    const int nblk_scan = (N_NODES + 1023) / 1024;  // 98

    hipMemsetAsync(cnt_s, 0, 2 * (size_t)N_NODES * 4, stream);

    embed_kernel<<<(N_NODES * 64 + 255) / 256, 256, 0, stream>>>(nodes, W_embed, b_embed, x, xb);
    edge_rank_kernel<<<(N_EDGES + 255) / 256, 256, 0, stream>>>(senders, receivers, cnt_s, cnt_r, rank);
    rsqrt_kernel<<<(N_NODES + 255) / 256, 256, 0, stream>>>(cnt_s, cnt_r, inv_s, inv_r);
    scan_blocksum<<<nblk_scan, 256, 0, stream>>>(cnt_r, partial);
    scan_partials<<<1, 64, 0, stream>>>(partial, nblk_scan);
    scan_final<<<nblk_scan, 256, 0, stream>>>(cnt_r, partial, row_ptr);
    scatter_csr<<<(N_EDGES + 255) / 256, 256, 0, stream>>>(senders, receivers, row_ptr, rank, col);
    wfrag_kernel<<<32, 256, 0, stream>>>(W_mlp0, W_mlp1, wfrag);

    for (int step = 0; step < N_STEPS; ++step) {
        mlp_mfma<<<1024, 256, 0, stream>>>(xb, h, wfrag, b_mlp0, b_mlp1, inv_s);
        agg_ln_kernel<<<2048, 256, 0, stream>>>(h, x, xb, row_ptr, col, inv_r, ln_scale, ln_bias);
    }

    pool_kernel<<<N_GRAPH, 256, 0, stream>>>(x, n_node, W_glob, b_glob, out);
}

// Round 6
// 509.980 us; speedup vs baseline: 1.8095x; 1.1746x over previous
//
#include <hip/hip_runtime.h>
#include <hip/hip_bf16.h>

#define N_NODES 100000
#define N_EDGES 1600000
#define LATENT 64
#define N_GRAPH 100
#define OUT_G 16
#define N_STEPS 3

// CSR-build geometry
#define NCHUNK 8
#define CHUNKN 12500            // nodes per chunk
#define CHUNKW 6250             // packed u16-pair words per chunk
#define NSLICE 64
#define SLICE_E 25000           // edges per slice

using bf16 = __hip_bfloat16;
using bf16x8 = __attribute__((ext_vector_type(8))) short;
using f32x4  = __attribute__((ext_vector_type(4))) float;

__device__ __forceinline__ float blo(unsigned int u) {
    union { unsigned int i; float f; } v; v.i = u << 16; return v.f;
}
__device__ __forceinline__ float bhi(unsigned int u) {
    union { unsigned int i; float f; } v; v.i = u & 0xffff0000u; return v.f;
}

// ---------------- K1: per-(chunk,slice) LDS histograms of senders+receivers ----
__global__ __launch_bounds__(256) void csr_hist(
    const int* __restrict__ senders, const int* __restrict__ receivers,
    unsigned int* __restrict__ histR_g, unsigned int* __restrict__ histS_g)
{
    __shared__ unsigned int hist[2 * CHUNKW];   // [0,CHUNKW) = R, [CHUNKW,2*CHUNKW) = S
    int c = blockIdx.x & (NCHUNK - 1), s = blockIdx.x >> 3;
    int t = threadIdx.x;
    for (int w = t; w < 2 * CHUNKW; w += 256) hist[w] = 0;
    __syncthreads();
    int base = s * SLICE_E;
    int lo = c * CHUNKN, hi_ = lo + CHUNKN;
    for (int e = base + t; e < base + SLICE_E; e += 256) {
        int r  = receivers[e];
        int sd = senders[e];
        if (r >= lo && r < hi_) {
            int rl = r - lo;
            atomicAdd(&hist[rl >> 1], (rl & 1) ? 65536u : 1u);
        }
        if (sd >= lo && sd < hi_) {
            int sl = sd - lo;
            atomicAdd(&hist[CHUNKW + (sl >> 1)], (sl & 1) ? 65536u : 1u);
        }
    }
    __syncthreads();
    unsigned int* outR = histR_g + (size_t)blockIdx.x * CHUNKW;
    unsigned int* outS = histS_g + (size_t)blockIdx.x * CHUNKW;
    for (int w = t; w < CHUNKW; w += 256) { outR[w] = hist[w]; outS[w] = hist[CHUNKW + w]; }
}

// ---------------- K2: scan slice-partials -> per-slice offsets + degree totals --
__global__ __launch_bounds__(256) void csr_scan_blocks(
    const unsigned int* __restrict__ histR_g, const unsigned int* __restrict__ histS_g,
    unsigned short* __restrict__ blockoffR, int* __restrict__ cnt_r, int* __restrict__ cnt_s)
{
    int tid = blockIdx.x * blockDim.x + threadIdx.x;
    if (tid >= NCHUNK * CHUNKW) return;
    int c = tid / CHUNKW, w = tid - c * CHUNKW;
    int node = c * CHUNKN + 2 * w;
    unsigned int runLo = 0, runHi = 0;
#pragma unroll 8
    for (int s = 0; s < NSLICE; s++) {
        unsigned int v = histR_g[(size_t)(s * NCHUNK + c) * CHUNKW + w];
        *(unsigned int*)&blockoffR[(size_t)s * N_NODES + node] =
            (runLo & 0xffffu) | (runHi << 16);
        runLo += v & 0xffffu; runHi += v >> 16;
    }
    ((int2*)cnt_r)[node >> 1] = make_int2((int)runLo, (int)runHi);
    runLo = runHi = 0;
#pragma unroll 8
    for (int s = 0; s < NSLICE; s++) {
        unsigned int v = histS_g[(size_t)(s * NCHUNK + c) * CHUNKW + w];
        runLo += v & 0xffffu; runHi += v >> 16;
    }
    ((int2*)cnt_s)[node >> 1] = make_int2((int)runLo, (int)runHi);
}

__global__ __launch_bounds__(256) void rsqrt_kernel(
    const int* __restrict__ cnt_s, const int* __restrict__ cnt_r,
    float* __restrict__ inv_s, float* __restrict__ inv_r)
{
    int i = blockIdx.x * blockDim.x + threadIdx.x;
    if (i >= N_NODES) return;
    inv_s[i] = rsqrtf((float)(cnt_s[i] + 1));
    inv_r[i] = rsqrtf((float)(cnt_r[i] + 1));
}

// ---------------- exclusive scan of cnt_r -> row_ptr ----------------
__global__ __launch_bounds__(256) void scan_blocksum(
    const int* __restrict__ cnt, int* __restrict__ partial)
{
    __shared__ int sred[256];
    int b = blockIdx.x, t = threadIdx.x;
    int base = b * 1024 + t * 4;
    int s = 0;
#pragma unroll
    for (int j = 0; j < 4; j++) {
        int i = base + j;
        s += (i < N_NODES) ? cnt[i] : 0;
    }
    sred[t] = s;
    __syncthreads();
    for (int off = 128; off > 0; off >>= 1) {
        if (t < off) sred[t] += sred[t + off];
        __syncthreads();
    }
    if (t == 0) partial[b] = sred[0];
}

__global__ void scan_partials(int* partial, int nblk)
{
    if (threadIdx.x == 0 && blockIdx.x == 0) {
        int run = 0;
        for (int b = 0; b < nblk; b++) { int v = partial[b]; partial[b] = run; run += v; }
    }
}

__global__ __launch_bounds__(256) void scan_final(
    const int* __restrict__ cnt, const int* __restrict__ partial,
    int* __restrict__ row_ptr)
{
    __shared__ int lds[256];
    int b = blockIdx.x, t = threadIdx.x;
    int base = b * 1024 + t * 4;
    int v[4]; int s = 0;
#pragma unroll
    for (int j = 0; j < 4; j++) {
        int i = base + j;
        v[j] = (i < N_NODES) ? cnt[i] : 0;
        s += v[j];
    }
    lds[t] = s;
    __syncthreads();
    for (int off = 1; off < 256; off <<= 1) {
        int add = (t >= off) ? lds[t - off] : 0;
        __syncthreads();
        lds[t] += add;
        __syncthreads();
    }
    int run = lds[t] - s + partial[b];
#pragma unroll
    for (int j = 0; j < 4; j++) {
        int i = base + j;
        if (i < N_NODES) {
            row_ptr[i] = run;
            run += v[j];
            if (i == N_NODES - 1) row_ptr[N_NODES] = run;
        }
    }
}

// ---------------- K3: scatter with LDS local ranks (no global atomics) --------
__global__ __launch_bounds__(256) void csr_scatter(
    const int* __restrict__ senders, const int* __restrict__ receivers,
    const int* __restrict__ row_ptr, const unsigned short* __restrict__ blockoffR,
    int* __restrict__ col)
{
    __shared__ unsigned int lrank[CHUNKW];
    int c = blockIdx.x & (NCHUNK - 1), s = blockIdx.x >> 3;
    int t = threadIdx.x;
    for (int w = t; w < CHUNKW; w += 256) lrank[w] = 0;
    __syncthreads();
    int base = s * SLICE_E;
    int lo = c * CHUNKN, hi_ = lo + CHUNKN;
    const unsigned short* boff = blockoffR + (size_t)s * N_NODES;
    for (int e = base + t; e < base + SLICE_E; e += 256) {
        int r  = receivers[e];
        int sd = senders[e];
        if (r >= lo && r < hi_) {
            int rl = r - lo;
            unsigned int old = atomicAdd(&lrank[rl >> 1], (rl & 1) ? 65536u : 1u);
            unsigned int lr = (rl & 1) ? (old >> 16) : (old & 0xffffu);
            col[row_ptr[r] + (int)boff[r] + (int)lr] = sd;
        }
    }
}

// ---------------- embed: x = nodes @ W_embed + b_embed (f32 + bf16 shadow) ----
__global__ __launch_bounds__(256) void embed_kernel(
    const float* __restrict__ nodes, const float* __restrict__ We,
    const float* __restrict__ be, float* __restrict__ x, bf16* __restrict__ xb)
{
    int tid = blockIdx.x * blockDim.x + threadIdx.x;
    if (tid >= N_NODES * 64) return;
    int i = tid >> 6, d = tid & 63;
    float acc = be[d];
    acc += nodes[i * 3 + 0] * We[0 * 64 + d];
    acc += nodes[i * 3 + 1] * We[1 * 64 + d];
    acc += nodes[i * 3 + 2] * We[2 * 64 + d];
    x[tid] = acc;
    xb[tid] = __float2bfloat16(acc);
}

// ---------------- W fragment pre-pack (f32 -> bf16, MFMA frag order) ----------
__global__ __launch_bounds__(256) void wfrag_kernel(
    const float* __restrict__ W0, const float* __restrict__ W1,
    bf16* __restrict__ frags)
{
    int tid = blockIdx.x * blockDim.x + threadIdx.x;
    if (tid >= 8192) return;
    int j    = tid & 7;
    int lane = (tid >> 3) & 63;
    int c    = (tid >> 9) & 1;
    int nt   = (tid >> 10) & 3;
    int L    = (tid >> 12) & 1;
    int g = lane >> 4, q = lane & 15;
    int k = c * 32 + g * 8 + j;
    int colIdx = nt * 16 + q;
    const float* W = L ? W1 : W0;
    frags[tid] = __float2bfloat16(W[k * 64 + colIdx]);
}

// ---------------- MFMA 2-layer MLP (+ inv_sqrt_s epilogue), bf16 ----------------
__global__ __launch_bounds__(256) void mlp_mfma(
    const bf16* __restrict__ xb, bf16* __restrict__ h,
    const bf16* __restrict__ wfrag,
    const float* __restrict__ b0, const float* __restrict__ b1,
    const float* __restrict__ inv_s)
{
    __shared__ char lds_raw[4][2048];
    int t = threadIdx.x;
    int w = t >> 6, lane = t & 63;
    int g = lane >> 4, q = lane & 15;
    char* myLds = lds_raw[w];

    bf16x8 wf[2][4][2];
#pragma unroll
    for (int L = 0; L < 2; L++)
#pragma unroll
        for (int nt = 0; nt < 4; nt++)
#pragma unroll
            for (int c = 0; c < 2; c++)
                wf[L][nt][c] = *(const bf16x8*)&wfrag[((((L * 4 + nt) * 2 + c) * 64) + lane) * 8];

    float bias0[4], bias1[4];
#pragma unroll
    for (int nt = 0; nt < 4; nt++) {
        bias0[nt] = b0[nt * 16 + q];
        bias1[nt] = b1[nt * 16 + q];
    }

    const int NTILES = N_NODES / 16;  // 6250
    for (int tile = blockIdx.x * 4 + w; tile < NTILES; tile += gridDim.x * 4) {
        int nodeBase = tile * 16;

        bf16x8 a0[2];
#pragma unroll
        for (int c = 0; c < 2; c++)
            a0[c] = *(const bf16x8*)&xb[(size_t)(nodeBase + q) * 64 + c * 32 + g * 8];

        f32x4 acc[4];
#pragma unroll
        for (int nt = 0; nt < 4; nt++) {
            acc[nt] = (f32x4){bias0[nt], bias0[nt], bias0[nt], bias0[nt]};
            acc[nt] = __builtin_amdgcn_mfma_f32_16x16x32_bf16(a0[0], wf[0][nt][0], acc[nt], 0, 0, 0);
            acc[nt] = __builtin_amdgcn_mfma_f32_16x16x32_bf16(a0[1], wf[0][nt][1], acc[nt], 0, 0, 0);
        }
#pragma unroll
        for (int nt = 0; nt < 4; nt++)
#pragma unroll
            for (int r = 0; r < 4; r++) {
                float v = fmaxf(acc[nt][r], 0.f);
                int node = g * 4 + r;
                int byte = ((node * 128 + (nt * 16 + q) * 2)) ^ ((node & 7) << 4);
                *(bf16*)(myLds + byte) = __float2bfloat16(v);
            }
        bf16x8 a1[2];
#pragma unroll
        for (int c = 0; c < 2; c++) {
            int byte = (q * 128 + c * 64 + g * 16) ^ ((q & 7) << 4);
            a1[c] = *(const bf16x8*)(myLds + byte);
        }

        f32x4 acc1[4];
#pragma unroll
        for (int nt = 0; nt < 4; nt++) {
            acc1[nt] = (f32x4){bias1[nt], bias1[nt], bias1[nt], bias1[nt]};
            acc1[nt] = __builtin_amdgcn_mfma_f32_16x16x32_bf16(a1[0], wf[1][nt][0], acc1[nt], 0, 0, 0);
            acc1[nt] = __builtin_amdgcn_mfma_f32_16x16x32_bf16(a1[1], wf[1][nt][1], acc1[nt], 0, 0, 0);
        }
        float is[4];
#pragma unroll
        for (int r = 0; r < 4; r++) is[r] = inv_s[nodeBase + g * 4 + r];
#pragma unroll
        for (int nt = 0; nt < 4; nt++)
#pragma unroll
            for (int r = 0; r < 4; r++) {
                float v = fmaxf(acc1[nt][r], 0.f) * is[r];
                int node = g * 4 + r;
                int byte = ((node * 128 + (nt * 16 + q) * 2)) ^ ((node & 7) << 4);
                *(bf16*)(myLds + byte) = __float2bfloat16(v);
            }
#pragma unroll
        for (int half = 0; half < 2; half++) {
            int byteL = lane * 32 + half * 16;
            int node = byteL >> 7;
            bf16x8 v = *(const bf16x8*)(myLds + (byteL ^ ((node & 7) << 4)));
            *(bf16x8*)&h[(size_t)nodeBase * 64 + lane * 16 + half * 8] = v;
        }
    }
}

// ---------------- gather-aggregate: 2 rows per VMEM instr + skip + LayerNorm ----
__global__ __launch_bounds__(256) void agg_ln_kernel(
    const bf16* __restrict__ h, float* __restrict__ x, bf16* __restrict__ xb,
    const int* __restrict__ row_ptr, const int* __restrict__ col,
    const float* __restrict__ inv_r,
    const float* __restrict__ ln_scale, const float* __restrict__ ln_bias)
{
    int t = threadIdx.x;
    int lane = t & 63;
    int sub = lane >> 5;          // which edge of the pair this half-wave handles
    int c = lane & 31;            // this lane covers columns 2c, 2c+1
    float2 lnsv = *(const float2*)&ln_scale[2 * c];
    float2 lnbv = *(const float2*)&ln_bias[2 * c];
    int gw = (blockIdx.x * blockDim.x + t) >> 6;
    int nwaves = (gridDim.x * blockDim.x) >> 6;
    for (int i = gw; i < N_NODES; i += nwaves) {
        float a0 = 0.f, a1 = 0.f, b0 = 0.f, b1 = 0.f;
        // self edge (inv_s already folded into h); count once via sub==0
        unsigned int su = *(const unsigned int*)&h[(size_t)i * 64 + 2 * c];
        if (sub == 0) { a0 += blo(su); a1 += bhi(su); }
        int beg = row_ptr[i], end = row_ptr[i + 1];
        int e = beg;
        for (; e + 8 <= end; e += 8) {
            int r0 = col[e + 0 + sub];
            int r1 = col[e + 2 + sub];
            int r2 = col[e + 4 + sub];
            int r3 = col[e + 6 + sub];
            unsigned int u0 = *(const unsigned int*)&h[(size_t)r0 * 64 + 2 * c];
            unsigned int u1 = *(const unsigned int*)&h[(size_t)r1 * 64 + 2 * c];
            unsigned int u2 = *(const unsigned int*)&h[(size_t)r2 * 64 + 2 * c];
            unsigned int u3 = *(const unsigned int*)&h[(size_t)r3 * 64 + 2 * c];
            a0 += blo(u0) + blo(u1);
            a1 += bhi(u0) + bhi(u1);
            b0 += blo(u2) + blo(u3);
            b1 += bhi(u2) + bhi(u3);
        }
        for (; e < end; e += 2) {
            int idx = e + sub;
            if (idx < end) {
                int r = col[idx];
                unsigned int u = *(const unsigned int*)&h[(size_t)r * 64 + 2 * c];
                a0 += blo(u); a1 += bhi(u);
            }
        }
        a0 += b0; a1 += b1;
        // merge the two half-wave partial sums
        a0 += __shfl_xor(a0, 32);
        a1 += __shfl_xor(a1, 32);
        float ir = inv_r[i];
        float2 xv = *(const float2*)&x[(size_t)i * 64 + 2 * c];
        float y0 = a0 * ir + xv.x;
        float y1 = a1 * ir + xv.y;
        // LayerNorm over 64 cols = 2 per lane x 32 lanes (duplicated across halves)
        float sum = y0 + y1;
#pragma unroll
        for (int m = 1; m < 32; m <<= 1) sum += __shfl_xor(sum, m);
        float mu = sum * (1.f / 64.f);
        float d0 = y0 - mu, d1 = y1 - mu;
        float vs = d0 * d0 + d1 * d1;
#pragma unroll
        for (int m = 1; m < 32; m <<= 1) vs += __shfl_xor(vs, m);
        float var = vs * (1.f / 64.f);
        float rr = rsqrtf(var + 1e-6f);
        float o0 = d0 * rr * lnsv.x + lnbv.x;
        float o1 = d1 * rr * lnsv.y + lnbv.y;
        if (sub == 0) {
            *(float2*)&x[(size_t)i * 64 + 2 * c] = make_float2(o0, o1);
            union { unsigned int u; bf16 h2[2]; } pk;
            pk.h2[0] = __float2bfloat16(o0);
            pk.h2[1] = __float2bfloat16(o1);
            *(unsigned int*)&xb[(size_t)i * 64 + 2 * c] = pk.u;
        }
    }
}

// ---------------- segment-mean pool + decoder ----------------
__global__ __launch_bounds__(256) void pool_kernel(
    const float* __restrict__ x, const int* __restrict__ n_node,
    const float* __restrict__ Wg, const float* __restrict__ bg,
    float* __restrict__ out)
{
    __shared__ float red[4][64];
    __shared__ float pd[64];
    int g = blockIdx.x;
    int t = threadIdx.x, w = t >> 6, lane = t & 63;
    int start = 0;
    for (int j = 0; j < g; j++) start += n_node[j];
    int cnt = n_node[g];
    float acc = 0.f;
    for (int j = w; j < cnt; j += 4) acc += x[(size_t)(start + j) * 64 + lane];
    red[w][lane] = acc;
    __syncthreads();
    if (w == 0) {
        float s = red[0][lane] + red[1][lane] + red[2][lane] + red[3][lane];
        pd[lane] = s / fmaxf((float)cnt, 1.f);
    }
    __syncthreads();
    if (t < OUT_G) {
        float v = bg[t];
#pragma unroll 16
        for (int dd = 0; dd < 64; dd++) v += pd[dd] * Wg[dd * OUT_G + t];
        out[g * OUT_G + t] = v;
    }
}

extern "C" void kernel_launch(void* const* d_in, const int* in_sizes, int n_in,
                              void* d_out, int out_size, void* d_ws, size_t ws_size,
                              hipStream_t stream) {
    const float* nodes    = (const float*)d_in[0];
    const int*   senders  = (const int*)d_in[1];
    const int*   receivers= (const int*)d_in[2];
    const int*   n_node   = (const int*)d_in[3];
    const float* W_embed  = (const float*)d_in[4];
    const float* b_embed  = (const float*)d_in[5];
    const float* W_mlp0   = (const float*)d_in[6];
    const float* b_mlp0   = (const float*)d_in[7];
    const float* W_mlp1   = (const float*)d_in[8];
    const float* b_mlp1   = (const float*)d_in[9];
    const float* ln_scale = (const float*)d_in[10];
    const float* ln_bias  = (const float*)d_in[11];
    const float* W_glob   = (const float*)d_in[12];
    const float* b_glob   = (const float*)d_in[13];
    float* out = (float*)d_out;

    // workspace layout (16B-aligned pieces)
    char* ws = (char*)d_ws;
    float* x      = (float*)ws;   ws += (size_t)N_NODES * 64 * 4;   // 25.6 MB
    bf16*  xb     = (bf16*)ws;    ws += (size_t)N_NODES * 64 * 2;   // 12.8 MB
    bf16*  h      = (bf16*)ws;    ws += (size_t)N_NODES * 64 * 2;   // 12.8 MB
    float* inv_s  = (float*)ws;   ws += (size_t)N_NODES * 4;
    float* inv_r  = (float*)ws;   ws += (size_t)N_NODES * 4;
    int*   cnt_s  = (int*)ws;     ws += (size_t)N_NODES * 4;
    int*   cnt_r  = (int*)ws;     ws += (size_t)N_NODES * 4;
    int*   row_ptr= (int*)ws;     ws += (size_t)(N_NODES + 4) * 4;
    int*   col    = (int*)ws;     ws += (size_t)N_EDGES * 4;
    int*   partial= (int*)ws;     ws += 256 * 4;
    bf16*  wfrag  = (bf16*)ws;    ws += 8192 * 2;

    // CSR-build temporaries alias x/xb (dead until embed, which runs after K3)
    unsigned int*   histR_g   = (unsigned int*)x;                               // 12.8 MB
    unsigned int*   histS_g   = (unsigned int*)((char*)x + (size_t)NSLICE * NCHUNK * CHUNKW * 4); // 12.8 MB
    unsigned short* blockoffR = (unsigned short*)xb;                            // 12.8 MB

    const int nblk_scan = (N_NODES + 1023) / 1024;  // 98

    // ---- CSR build (no global atomics) ----
    csr_hist<<<NSLICE * NCHUNK, 256, 0, stream>>>(senders, receivers, histR_g, histS_g);
    csr_scan_blocks<<<(NCHUNK * CHUNKW + 255) / 256, 256, 0, stream>>>(
        histR_g, histS_g, blockoffR, cnt_r, cnt_s);
    rsqrt_kernel<<<(N_NODES + 255) / 256, 256, 0, stream>>>(cnt_s, cnt_r, inv_s, inv_r);
    scan_blocksum<<<nblk_scan, 256, 0, stream>>>(cnt_r, partial);
    scan_partials<<<1, 64, 0, stream>>>(partial, nblk_scan);
    scan_final<<<nblk_scan, 256, 0, stream>>>(cnt_r, partial, row_ptr);
    csr_scatter<<<NSLICE * NCHUNK, 256, 0, stream>>>(senders, receivers, row_ptr, blockoffR, col);

    // ---- embed (after CSR temporaries are dead) ----
    embed_kernel<<<(N_NODES * 64 + 255) / 256, 256, 0, stream>>>(nodes, W_embed, b_embed, x, xb);
    wfrag_kernel<<<32, 256, 0, stream>>>(W_mlp0, W_mlp1, wfrag);

    for (int step = 0; step < N_STEPS; ++step) {
        mlp_mfma<<<1024, 256, 0, stream>>>(xb, h, wfrag, b_mlp0, b_mlp1, inv_s);
        agg_ln_kernel<<<2048, 256, 0, stream>>>(h, x, xb, row_ptr, col, inv_r, ln_scale, ln_bias);
    }

    pool_kernel<<<N_GRAPH, 256, 0, stream>>>(x, n_node, W_glob, b_glob, out);
}

// Round 7
// 472.055 us; speedup vs baseline: 1.9549x; 1.0803x over previous
//
#include <hip/hip_runtime.h>
#include <hip/hip_bf16.h>

#define N_NODES 100000
#define N_EDGES 1600000
#define LATENT 64
#define N_GRAPH 100
#define OUT_G 16
#define N_STEPS 3

// CSR-build geometry
#define NCHUNK 4
#define CHUNKN 25000            // nodes per chunk
#define CHUNKW 12500            // packed u16-pair words per chunk (50 KB LDS)
#define NSLICE 64
#define SLICE_E 25000           // edges per slice

using bf16 = __hip_bfloat16;
using bf16x8 = __attribute__((ext_vector_type(8))) short;
using f32x4  = __attribute__((ext_vector_type(4))) float;

__device__ __forceinline__ float blo(unsigned int u) {
    union { unsigned int i; float f; } v; v.i = u << 16; return v.f;
}
__device__ __forceinline__ float bhi(unsigned int u) {
    union { unsigned int i; float f; } v; v.i = u & 0xffff0000u; return v.f;
}

// ---------------- K1: per-(chunk,slice) LDS histogram of one index array ------
__global__ __launch_bounds__(512) void csr_hist1(
    const int* __restrict__ idx, unsigned int* __restrict__ hist_g)
{
    __shared__ unsigned int hist[CHUNKW];   // 50 KB
    int c = blockIdx.x & (NCHUNK - 1), s = blockIdx.x >> 2;
    int t = threadIdx.x;
    for (int w = t; w < CHUNKW; w += 512) hist[w] = 0;
    __syncthreads();
    int base = s * SLICE_E;
    int lo = c * CHUNKN;
    for (int e = base + t; e < base + SLICE_E; e += 512) {
        unsigned int rl = (unsigned int)(idx[e] - lo);
        if (rl < CHUNKN) atomicAdd(&hist[rl >> 1], (rl & 1) ? 65536u : 1u);
    }
    __syncthreads();
    unsigned int* outp = hist_g + (size_t)blockIdx.x * CHUNKW;
    for (int w = t; w < CHUNKW; w += 512) outp[w] = hist[w];
}

// ---------------- K2: scan slice-partials -> offsets + cnt_r + inv_r/inv_s ----
__global__ __launch_bounds__(256) void csr_scan_blocks(
    const unsigned int* __restrict__ histR_g, const unsigned int* __restrict__ histS_g,
    unsigned short* __restrict__ blockoffR, int* __restrict__ cnt_r,
    float* __restrict__ inv_r, float* __restrict__ inv_s)
{
    int tid = blockIdx.x * blockDim.x + threadIdx.x;
    if (tid >= NCHUNK * CHUNKW) return;
    int c = tid / CHUNKW, w = tid - c * CHUNKW;
    int node = c * CHUNKN + 2 * w;
    unsigned int runLo = 0, runHi = 0;
#pragma unroll 8
    for (int s = 0; s < NSLICE; s++) {
        unsigned int v = histR_g[(size_t)(s * NCHUNK + c) * CHUNKW + w];
        *(unsigned int*)&blockoffR[(size_t)s * N_NODES + node] =
            (runLo & 0xffffu) | (runHi << 16);
        runLo += v & 0xffffu; runHi += v >> 16;
    }
    ((int2*)cnt_r)[node >> 1] = make_int2((int)runLo, (int)runHi);
    ((float2*)inv_r)[node >> 1] =
        make_float2(rsqrtf((float)(runLo + 1)), rsqrtf((float)(runHi + 1)));
    runLo = runHi = 0;
#pragma unroll 8
    for (int s = 0; s < NSLICE; s++) {
        unsigned int v = histS_g[(size_t)(s * NCHUNK + c) * CHUNKW + w];
        runLo += v & 0xffffu; runHi += v >> 16;
    }
    ((float2*)inv_s)[node >> 1] =
        make_float2(rsqrtf((float)(runLo + 1)), rsqrtf((float)(runHi + 1)));
}

// ---------------- exclusive scan of cnt_r -> row_ptr ----------------
__global__ __launch_bounds__(256) void scan_blocksum(
    const int* __restrict__ cnt, int* __restrict__ partial)
{
    __shared__ int sred[256];
    int b = blockIdx.x, t = threadIdx.x;
    int base = b * 1024 + t * 4;
    int s = 0;
#pragma unroll
    for (int j = 0; j < 4; j++) {
        int i = base + j;
        s += (i < N_NODES) ? cnt[i] : 0;
    }
    sred[t] = s;
    __syncthreads();
    for (int off = 128; off > 0; off >>= 1) {
        if (t < off) sred[t] += sred[t + off];
        __syncthreads();
    }
    if (t == 0) partial[b] = sred[0];
}

__global__ void scan_partials(int* partial, int nblk)
{
    if (threadIdx.x == 0 && blockIdx.x == 0) {
        int run = 0;
        for (int b = 0; b < nblk; b++) { int v = partial[b]; partial[b] = run; run += v; }
    }
}

__global__ __launch_bounds__(256) void scan_final(
    const int* __restrict__ cnt, const int* __restrict__ partial,
    int* __restrict__ row_ptr)
{
    __shared__ int lds[256];
    int b = blockIdx.x, t = threadIdx.x;
    int base = b * 1024 + t * 4;
    int v[4]; int s = 0;
#pragma unroll
    for (int j = 0; j < 4; j++) {
        int i = base + j;
        v[j] = (i < N_NODES) ? cnt[i] : 0;
        s += v[j];
    }
    lds[t] = s;
    __syncthreads();
    for (int off = 1; off < 256; off <<= 1) {
        int add = (t >= off) ? lds[t - off] : 0;
        __syncthreads();
        lds[t] += add;
        __syncthreads();
    }
    int run = lds[t] - s + partial[b];
#pragma unroll
    for (int j = 0; j < 4; j++) {
        int i = base + j;
        if (i < N_NODES) {
            row_ptr[i] = run;
            run += v[j];
            if (i == N_NODES - 1) row_ptr[N_NODES] = run;
        }
    }
}

// ---------------- K3: scatter with LDS local ranks (no global atomics) --------
__global__ __launch_bounds__(512) void csr_scatter(
    const int* __restrict__ senders, const int* __restrict__ receivers,
    const int* __restrict__ row_ptr, const unsigned short* __restrict__ blockoffR,
    int* __restrict__ col)
{
    __shared__ unsigned int lrank[CHUNKW];   // 50 KB
    int c = blockIdx.x & (NCHUNK - 1), s = blockIdx.x >> 2;
    int t = threadIdx.x;
    for (int w = t; w < CHUNKW; w += 512) lrank[w] = 0;
    __syncthreads();
    int base = s * SLICE_E;
    int lo = c * CHUNKN;
    const unsigned short* boff = blockoffR + (size_t)s * N_NODES;
    for (int e = base + t; e < base + SLICE_E; e += 512) {
        int r  = receivers[e];
        int sd = senders[e];
        unsigned int rl = (unsigned int)(r - lo);
        if (rl < CHUNKN) {
            unsigned int old = atomicAdd(&lrank[rl >> 1], (rl & 1) ? 65536u : 1u);
            unsigned int lr = (rl & 1) ? (old >> 16) : (old & 0xffffu);
            col[row_ptr[r] + (int)boff[r] + (int)lr] = sd;
        }
    }
}

// ---------------- embed: xb = bf16(nodes @ W_embed + b_embed) ----------------
__global__ __launch_bounds__(256) void embed_kernel(
    const float* __restrict__ nodes, const float* __restrict__ We,
    const float* __restrict__ be, bf16* __restrict__ xb)
{
    int tid = blockIdx.x * blockDim.x + threadIdx.x;
    if (tid >= N_NODES * 64) return;
    int i = tid >> 6, d = tid & 63;
    float acc = be[d];
    acc += nodes[i * 3 + 0] * We[0 * 64 + d];
    acc += nodes[i * 3 + 1] * We[1 * 64 + d];
    acc += nodes[i * 3 + 2] * We[2 * 64 + d];
    xb[tid] = __float2bfloat16(acc);
}

// ---------------- W fragment pre-pack (f32 -> bf16, MFMA frag order) ----------
__global__ __launch_bounds__(256) void wfrag_kernel(
    const float* __restrict__ W0, const float* __restrict__ W1,
    bf16* __restrict__ frags)
{
    int tid = blockIdx.x * blockDim.x + threadIdx.x;
    if (tid >= 8192) return;
    int j    = tid & 7;
    int lane = (tid >> 3) & 63;
    int c    = (tid >> 9) & 1;
    int nt   = (tid >> 10) & 3;
    int L    = (tid >> 12) & 1;
    int g = lane >> 4, q = lane & 15;
    int k = c * 32 + g * 8 + j;
    int colIdx = nt * 16 + q;
    const float* W = L ? W1 : W0;
    frags[tid] = __float2bfloat16(W[k * 64 + colIdx]);
}

// ---------------- MFMA 2-layer MLP (+ inv_sqrt_s epilogue), bf16 ----------------
__global__ __launch_bounds__(256) void mlp_mfma(
    const bf16* __restrict__ xb, bf16* __restrict__ h,
    const bf16* __restrict__ wfrag,
    const float* __restrict__ b0, const float* __restrict__ b1,
    const float* __restrict__ inv_s)
{
    __shared__ char lds_raw[4][2048];
    int t = threadIdx.x;
    int w = t >> 6, lane = t & 63;
    int g = lane >> 4, q = lane & 15;
    char* myLds = lds_raw[w];

    bf16x8 wf[2][4][2];
#pragma unroll
    for (int L = 0; L < 2; L++)
#pragma unroll
        for (int nt = 0; nt < 4; nt++)
#pragma unroll
            for (int c = 0; c < 2; c++)
                wf[L][nt][c] = *(const bf16x8*)&wfrag[((((L * 4 + nt) * 2 + c) * 64) + lane) * 8];

    float bias0[4], bias1[4];
#pragma unroll
    for (int nt = 0; nt < 4; nt++) {
        bias0[nt] = b0[nt * 16 + q];
        bias1[nt] = b1[nt * 16 + q];
    }

    const int NTILES = N_NODES / 16;  // 6250
    for (int tile = blockIdx.x * 4 + w; tile < NTILES; tile += gridDim.x * 4) {
        int nodeBase = tile * 16;

        bf16x8 a0[2];
#pragma unroll
        for (int c = 0; c < 2; c++)
            a0[c] = *(const bf16x8*)&xb[(size_t)(nodeBase + q) * 64 + c * 32 + g * 8];

        f32x4 acc[4];
#pragma unroll
        for (int nt = 0; nt < 4; nt++) {
            acc[nt] = (f32x4){bias0[nt], bias0[nt], bias0[nt], bias0[nt]};
            acc[nt] = __builtin_amdgcn_mfma_f32_16x16x32_bf16(a0[0], wf[0][nt][0], acc[nt], 0, 0, 0);
            acc[nt] = __builtin_amdgcn_mfma_f32_16x16x32_bf16(a0[1], wf[0][nt][1], acc[nt], 0, 0, 0);
        }
#pragma unroll
        for (int nt = 0; nt < 4; nt++)
#pragma unroll
            for (int r = 0; r < 4; r++) {
                float v = fmaxf(acc[nt][r], 0.f);
                int node = g * 4 + r;
                int byte = ((node * 128 + (nt * 16 + q) * 2)) ^ ((node & 7) << 4);
                *(bf16*)(myLds + byte) = __float2bfloat16(v);
            }
        bf16x8 a1[2];
#pragma unroll
        for (int c = 0; c < 2; c++) {
            int byte = (q * 128 + c * 64 + g * 16) ^ ((q & 7) << 4);
            a1[c] = *(const bf16x8*)(myLds + byte);
        }

        f32x4 acc1[4];
#pragma unroll
        for (int nt = 0; nt < 4; nt++) {
            acc1[nt] = (f32x4){bias1[nt], bias1[nt], bias1[nt], bias1[nt]};
            acc1[nt] = __builtin_amdgcn_mfma_f32_16x16x32_bf16(a1[0], wf[1][nt][0], acc1[nt], 0, 0, 0);
            acc1[nt] = __builtin_amdgcn_mfma_f32_16x16x32_bf16(a1[1], wf[1][nt][1], acc1[nt], 0, 0, 0);
        }
        float is[4];
#pragma unroll
        for (int r = 0; r < 4; r++) is[r] = inv_s[nodeBase + g * 4 + r];
#pragma unroll
        for (int nt = 0; nt < 4; nt++)
#pragma unroll
            for (int r = 0; r < 4; r++) {
                float v = fmaxf(acc1[nt][r], 0.f) * is[r];
                int node = g * 4 + r;
                int byte = ((node * 128 + (nt * 16 + q) * 2)) ^ ((node & 7) << 4);
                *(bf16*)(myLds + byte) = __float2bfloat16(v);
            }
#pragma unroll
        for (int half = 0; half < 2; half++) {
            int byteL = lane * 32 + half * 16;
            int node = byteL >> 7;
            bf16x8 v = *(const bf16x8*)(myLds + (byteL ^ ((node & 7) << 4)));
            *(bf16x8*)&h[(size_t)nodeBase * 64 + lane * 16 + half * 8] = v;
        }
    }
}

// ---------------- gather-aggregate: 2 rows/VMEM + bf16 skip + LayerNorm -------
__global__ __launch_bounds__(256) void agg_ln_kernel(
    const bf16* __restrict__ h, bf16* __restrict__ xb,
    const int* __restrict__ row_ptr, const int* __restrict__ col,
    const float* __restrict__ inv_r,
    const float* __restrict__ ln_scale, const float* __restrict__ ln_bias)
{
    int t = threadIdx.x;
    int lane = t & 63;
    int sub = lane >> 5;          // which edge of the pair this half-wave handles
    int c = lane & 31;            // this lane covers columns 2c, 2c+1
    float2 lnsv = *(const float2*)&ln_scale[2 * c];
    float2 lnbv = *(const float2*)&ln_bias[2 * c];
    int gw = (blockIdx.x * blockDim.x + t) >> 6;
    int nwaves = (gridDim.x * blockDim.x) >> 6;
    for (int i = gw; i < N_NODES; i += nwaves) {
        float a0 = 0.f, a1 = 0.f, b0 = 0.f, b1 = 0.f;
        // self edge (inv_s already folded into h); count once via sub==0
        unsigned int su = *(const unsigned int*)&h[(size_t)i * 64 + 2 * c];
        if (sub == 0) { a0 += blo(su); a1 += bhi(su); }
        int beg = row_ptr[i], end = row_ptr[i + 1];
        int e = beg;
        for (; e + 8 <= end; e += 8) {
            int r0 = col[e + 0 + sub];
            int r1 = col[e + 2 + sub];
            int r2 = col[e + 4 + sub];
            int r3 = col[e + 6 + sub];
            unsigned int u0 = *(const unsigned int*)&h[(size_t)r0 * 64 + 2 * c];
            unsigned int u1 = *(const unsigned int*)&h[(size_t)r1 * 64 + 2 * c];
            unsigned int u2 = *(const unsigned int*)&h[(size_t)r2 * 64 + 2 * c];
            unsigned int u3 = *(const unsigned int*)&h[(size_t)r3 * 64 + 2 * c];
            a0 += blo(u0) + blo(u1);
            a1 += bhi(u0) + bhi(u1);
            b0 += blo(u2) + blo(u3);
            b1 += bhi(u2) + bhi(u3);
        }
        for (; e < end; e += 2) {
            int idx = e + sub;
            if (idx < end) {
                int r = col[idx];
                unsigned int u = *(const unsigned int*)&h[(size_t)r * 64 + 2 * c];
                a0 += blo(u); a1 += bhi(u);
            }
        }
        a0 += b0; a1 += b1;
        // merge the two half-wave partial sums
        a0 += __shfl_xor(a0, 32);
        a1 += __shfl_xor(a1, 32);
        float ir = inv_r[i];
        unsigned int xu = *(const unsigned int*)&xb[(size_t)i * 64 + 2 * c];
        float y0 = a0 * ir + blo(xu);
        float y1 = a1 * ir + bhi(xu);
        // LayerNorm over 64 cols = 2 per lane x 32 lanes (duplicated across halves)
        float sum = y0 + y1;
#pragma unroll
        for (int m = 1; m < 32; m <<= 1) sum += __shfl_xor(sum, m);
        float mu = sum * (1.f / 64.f);
        float d0 = y0 - mu, d1 = y1 - mu;
        float vs = d0 * d0 + d1 * d1;
#pragma unroll
        for (int m = 1; m < 32; m <<= 1) vs += __shfl_xor(vs, m);
        float var = vs * (1.f / 64.f);
        float rr = rsqrtf(var + 1e-6f);
        float o0 = d0 * rr * lnsv.x + lnbv.x;
        float o1 = d1 * rr * lnsv.y + lnbv.y;
        if (sub == 0) {
            union { unsigned int u; bf16 h2[2]; } pk;
            pk.h2[0] = __float2bfloat16(o0);
            pk.h2[1] = __float2bfloat16(o1);
            *(unsigned int*)&xb[(size_t)i * 64 + 2 * c] = pk.u;
        }
    }
}

// ---------------- segment-mean pool + decoder (bf16 input) ----------------
__global__ __launch_bounds__(256) void pool_kernel(
    const bf16* __restrict__ xb, const int* __restrict__ n_node,
    const float* __restrict__ Wg, const float* __restrict__ bg,
    float* __restrict__ out)
{
    __shared__ float red[4][64];
    __shared__ float pd[64];
    int g = blockIdx.x;
    int t = threadIdx.x, w = t >> 6, lane = t & 63;
    int start = 0;
    for (int j = 0; j < g; j++) start += n_node[j];
    int cnt = n_node[g];
    float acc = 0.f;
    for (int j = w; j < cnt; j += 4)
        acc += __bfloat162float(xb[(size_t)(start + j) * 64 + lane]);
    red[w][lane] = acc;
    __syncthreads();
    if (w == 0) {
        float s = red[0][lane] + red[1][lane] + red[2][lane] + red[3][lane];
        pd[lane] = s / fmaxf((float)cnt, 1.f);
    }
    __syncthreads();
    if (t < OUT_G) {
        float v = bg[t];
#pragma unroll 16
        for (int dd = 0; dd < 64; dd++) v += pd[dd] * Wg[dd * OUT_G + t];
        out[g * OUT_G + t] = v;
    }
}

extern "C" void kernel_launch(void* const* d_in, const int* in_sizes, int n_in,
                              void* d_out, int out_size, void* d_ws, size_t ws_size,
                              hipStream_t stream) {
    const float* nodes    = (const float*)d_in[0];
    const int*   senders  = (const int*)d_in[1];
    const int*   receivers= (const int*)d_in[2];
    const int*   n_node   = (const int*)d_in[3];
    const float* W_embed  = (const float*)d_in[4];
    const float* b_embed  = (const float*)d_in[5];
    const float* W_mlp0   = (const float*)d_in[6];
    const float* b_mlp0   = (const float*)d_in[7];
    const float* W_mlp1   = (const float*)d_in[8];
    const float* b_mlp1   = (const float*)d_in[9];
    const float* ln_scale = (const float*)d_in[10];
    const float* ln_bias  = (const float*)d_in[11];
    const float* W_glob   = (const float*)d_in[12];
    const float* b_glob   = (const float*)d_in[13];
    float* out = (float*)d_out;

    // workspace layout (16B-aligned pieces)
    char* ws = (char*)d_ws;
    bf16*  xb     = (bf16*)ws;    ws += (size_t)N_NODES * 64 * 2;   // 12.8 MB
    bf16*  h      = (bf16*)ws;    ws += (size_t)N_NODES * 64 * 2;   // 12.8 MB
    unsigned int* histS_g = (unsigned int*)ws; ws += (size_t)NSLICE * NCHUNK * CHUNKW * 4; // 12.8 MB
    float* inv_s  = (float*)ws;   ws += (size_t)N_NODES * 4;
    float* inv_r  = (float*)ws;   ws += (size_t)N_NODES * 4;
    int*   cnt_r  = (int*)ws;     ws += (size_t)N_NODES * 4;
    int*   row_ptr= (int*)ws;     ws += (size_t)(N_NODES + 4) * 4;
    int*   col    = (int*)ws;     ws += (size_t)N_EDGES * 4;
    int*   partial= (int*)ws;     ws += 256 * 4;
    bf16*  wfrag  = (bf16*)ws;    ws += 8192 * 2;

    // CSR-build temporaries alias h/xb (dead until the step loop)
    unsigned int*   histR_g   = (unsigned int*)h;     // 12.8 MB, read before mlp writes h
    unsigned short* blockoffR = (unsigned short*)xb;  // 12.8 MB, read before embed writes xb

    const int nblk_scan = (N_NODES + 1023) / 1024;  // 98

    // ---- CSR build (no global atomics) ----
    csr_hist1<<<NSLICE * NCHUNK, 512, 0, stream>>>(receivers, histR_g);
    csr_hist1<<<NSLICE * NCHUNK, 512, 0, stream>>>(senders, histS_g);
    csr_scan_blocks<<<(NCHUNK * CHUNKW + 255) / 256, 256, 0, stream>>>(
        histR_g, histS_g, blockoffR, cnt_r, inv_r, inv_s);
    scan_blocksum<<<nblk_scan, 256, 0, stream>>>(cnt_r, partial);
    scan_partials<<<1, 64, 0, stream>>>(partial, nblk_scan);
    scan_final<<<nblk_scan, 256, 0, stream>>>(cnt_r, partial, row_ptr);
    csr_scatter<<<NSLICE * NCHUNK, 512, 0, stream>>>(senders, receivers, row_ptr, blockoffR, col);

    // ---- embed (after CSR temporaries are dead) ----
    embed_kernel<<<(N_NODES * 64 + 255) / 256, 256, 0, stream>>>(nodes, W_embed, b_embed, xb);
    wfrag_kernel<<<32, 256, 0, stream>>>(W_mlp0, W_mlp1, wfrag);

    for (int step = 0; step < N_STEPS; ++step) {
        mlp_mfma<<<1024, 256, 0, stream>>>(xb, h, wfrag, b_mlp0, b_mlp1, inv_s);
        agg_ln_kernel<<<2048, 256, 0, stream>>>(h, xb, row_ptr, col, inv_r, ln_scale, ln_bias);
    }

    pool_kernel<<<N_GRAPH, 256, 0, stream>>>(xb, n_node, W_glob, b_glob, out);
}

// Round 8
// 406.442 us; speedup vs baseline: 2.2705x; 1.1614x over previous
//
#include <hip/hip_runtime.h>
#include <hip/hip_bf16.h>

#define N_NODES 100000
#define N_EDGES 1600000
#define LATENT 64
#define N_GRAPH 100
#define OUT_G 16
#define N_STEPS 3

// CSR-build geometry
#define NCHUNK 4
#define CHUNKN 25000            // nodes per chunk
#define CHUNKW 12500            // packed u16-pair words per chunk (50 KB LDS)
#define NSLICE 64
#define SLICE_E 25000           // edges per slice

#define POOL_PB 8               // stage-1 blocks per graph

using bf16 = __hip_bfloat16;
using bf16x8 = __attribute__((ext_vector_type(8))) short;
using f32x4  = __attribute__((ext_vector_type(4))) float;

__device__ __forceinline__ float blo(unsigned int u) {
    union { unsigned int i; float f; } v; v.i = u << 16; return v.f;
}
__device__ __forceinline__ float bhi(unsigned int u) {
    union { unsigned int i; float f; } v; v.i = u & 0xffff0000u; return v.f;
}
__device__ __forceinline__ float bf2f(short s) {
    union { unsigned int i; float f; } v; v.i = ((unsigned int)(unsigned short)s) << 16; return v.f;
}

// ---------------- K1: per-(chunk,slice) LDS histogram of one index array ------
__global__ __launch_bounds__(512) void csr_hist1(
    const int* __restrict__ idx, unsigned int* __restrict__ hist_g)
{
    __shared__ unsigned int hist[CHUNKW];   // 50 KB
    int c = blockIdx.x & (NCHUNK - 1), s = blockIdx.x >> 2;
    int t = threadIdx.x;
    for (int w = t; w < CHUNKW; w += 512) hist[w] = 0;
    __syncthreads();
    int base = s * SLICE_E;
    int lo = c * CHUNKN;
    for (int e = base + t; e < base + SLICE_E; e += 512) {
        unsigned int rl = (unsigned int)(idx[e] - lo);
        if (rl < CHUNKN) atomicAdd(&hist[rl >> 1], (rl & 1) ? 65536u : 1u);
    }
    __syncthreads();
    unsigned int* outp = hist_g + (size_t)blockIdx.x * CHUNKW;
    for (int w = t; w < CHUNKW; w += 512) outp[w] = hist[w];
}

// ---------------- K2: scan slice-partials -> offsets + cnt_r + inv_r/inv_s ----
__global__ __launch_bounds__(256) void csr_scan_blocks(
    const unsigned int* __restrict__ histR_g, const unsigned int* __restrict__ histS_g,
    unsigned short* __restrict__ blockoffR, int* __restrict__ cnt_r,
    float* __restrict__ inv_r, float* __restrict__ inv_s)
{
    int tid = blockIdx.x * blockDim.x + threadIdx.x;
    if (tid >= NCHUNK * CHUNKW) return;
    int c = tid / CHUNKW, w = tid - c * CHUNKW;
    int node = c * CHUNKN + 2 * w;
    unsigned int runLo = 0, runHi = 0;
#pragma unroll 8
    for (int s = 0; s < NSLICE; s++) {
        unsigned int v = histR_g[(size_t)(s * NCHUNK + c) * CHUNKW + w];
        *(unsigned int*)&blockoffR[(size_t)s * N_NODES + node] =
            (runLo & 0xffffu) | (runHi << 16);
        runLo += v & 0xffffu; runHi += v >> 16;
    }
    ((int2*)cnt_r)[node >> 1] = make_int2((int)runLo, (int)runHi);
    ((float2*)inv_r)[node >> 1] =
        make_float2(rsqrtf((float)(runLo + 1)), rsqrtf((float)(runHi + 1)));
    runLo = runHi = 0;
#pragma unroll 8
    for (int s = 0; s < NSLICE; s++) {
        unsigned int v = histS_g[(size_t)(s * NCHUNK + c) * CHUNKW + w];
        runLo += v & 0xffffu; runHi += v >> 16;
    }
    ((float2*)inv_s)[node >> 1] =
        make_float2(rsqrtf((float)(runLo + 1)), rsqrtf((float)(runHi + 1)));
}

// ---------------- exclusive scan of cnt_r -> row_ptr ----------------
__global__ __launch_bounds__(256) void scan_blocksum(
    const int* __restrict__ cnt, int* __restrict__ partial)
{
    __shared__ int sred[256];
    int b = blockIdx.x, t = threadIdx.x;
    int base = b * 1024 + t * 4;
    int s = 0;
#pragma unroll
    for (int j = 0; j < 4; j++) {
        int i = base + j;
        s += (i < N_NODES) ? cnt[i] : 0;
    }
    sred[t] = s;
    __syncthreads();
    for (int off = 128; off > 0; off >>= 1) {
        if (t < off) sred[t] += sred[t + off];
        __syncthreads();
    }
    if (t == 0) partial[b] = sred[0];
}

// parallel exclusive scan of the 98 block partials (one 128-thread block)
__global__ __launch_bounds__(128) void scan_partials_par(int* partial, int nblk)
{
    __shared__ int lds[128];
    int t = threadIdx.x;
    int v = (t < nblk) ? partial[t] : 0;
    lds[t] = v;
    __syncthreads();
    for (int off = 1; off < 128; off <<= 1) {
        int add = (t >= off) ? lds[t - off] : 0;
        __syncthreads();
        lds[t] += add;
        __syncthreads();
    }
    if (t < nblk) partial[t] = lds[t] - v;   // exclusive
}

__global__ __launch_bounds__(256) void scan_final(
    const int* __restrict__ cnt, const int* __restrict__ partial,
    int* __restrict__ row_ptr)
{
    __shared__ int lds[256];
    int b = blockIdx.x, t = threadIdx.x;
    int base = b * 1024 + t * 4;
    int v[4]; int s = 0;
#pragma unroll
    for (int j = 0; j < 4; j++) {
        int i = base + j;
        v[j] = (i < N_NODES) ? cnt[i] : 0;
        s += v[j];
    }
    lds[t] = s;
    __syncthreads();
    for (int off = 1; off < 256; off <<= 1) {
        int add = (t >= off) ? lds[t - off] : 0;
        __syncthreads();
        lds[t] += add;
        __syncthreads();
    }
    int run = lds[t] - s + partial[b];
#pragma unroll
    for (int j = 0; j < 4; j++) {
        int i = base + j;
        if (i < N_NODES) {
            row_ptr[i] = run;
            run += v[j];
            if (i == N_NODES - 1) row_ptr[N_NODES] = run;
        }
    }
}

// ---------------- K3: scatter with LDS local ranks (no global atomics) --------
__global__ __launch_bounds__(512) void csr_scatter(
    const int* __restrict__ senders, const int* __restrict__ receivers,
    const int* __restrict__ row_ptr, const unsigned short* __restrict__ blockoffR,
    int* __restrict__ col)
{
    __shared__ unsigned int lrank[CHUNKW];   // 50 KB
    int c = blockIdx.x & (NCHUNK - 1), s = blockIdx.x >> 2;
    int t = threadIdx.x;
    for (int w = t; w < CHUNKW; w += 512) lrank[w] = 0;
    __syncthreads();
    int base = s * SLICE_E;
    int lo = c * CHUNKN;
    const unsigned short* boff = blockoffR + (size_t)s * N_NODES;
    for (int e = base + t; e < base + SLICE_E; e += 512) {
        int r  = receivers[e];
        int sd = senders[e];
        unsigned int rl = (unsigned int)(r - lo);
        if (rl < CHUNKN) {
            unsigned int old = atomicAdd(&lrank[rl >> 1], (rl & 1) ? 65536u : 1u);
            unsigned int lr = (rl & 1) ? (old >> 16) : (old & 0xffffu);
            col[row_ptr[r] + (int)boff[r] + (int)lr] = sd;
        }
    }
}

// ---------------- embed: xb = bf16(nodes @ W_embed + b_embed), vectorized -----
__global__ __launch_bounds__(256) void embed_kernel(
    const float* __restrict__ nodes, const float* __restrict__ We,
    const float* __restrict__ be, bf16* __restrict__ xb)
{
    int tid = blockIdx.x * blockDim.x + threadIdx.x;   // (node, col-chunk of 8)
    if (tid >= N_NODES * 8) return;
    int i = tid >> 3, cc = tid & 7;
    float n0 = nodes[i * 3 + 0], n1 = nodes[i * 3 + 1], n2 = nodes[i * 3 + 2];
    union { bf16x8 v; bf16 h[8]; } pk;
#pragma unroll
    for (int k = 0; k < 8; k++) {
        int d = cc * 8 + k;
        float acc = be[d] + n0 * We[0 * 64 + d] + n1 * We[1 * 64 + d] + n2 * We[2 * 64 + d];
        pk.h[k] = __float2bfloat16(acc);
    }
    *(bf16x8*)&xb[(size_t)i * 64 + cc * 8] = pk.v;
}

// ---------------- W fragment pre-pack (f32 -> bf16, MFMA frag order) ----------
__global__ __launch_bounds__(256) void wfrag_kernel(
    const float* __restrict__ W0, const float* __restrict__ W1,
    bf16* __restrict__ frags)
{
    int tid = blockIdx.x * blockDim.x + threadIdx.x;
    if (tid >= 8192) return;
    int j    = tid & 7;
    int lane = (tid >> 3) & 63;
    int c    = (tid >> 9) & 1;
    int nt   = (tid >> 10) & 3;
    int L    = (tid >> 12) & 1;
    int g = lane >> 4, q = lane & 15;
    int k = c * 32 + g * 8 + j;
    int colIdx = nt * 16 + q;
    const float* W = L ? W1 : W0;
    frags[tid] = __float2bfloat16(W[k * 64 + colIdx]);
}

// ---------------- MFMA 2-layer MLP (+ inv_sqrt_s epilogue), bf16 ----------------
__global__ __launch_bounds__(256) void mlp_mfma(
    const bf16* __restrict__ xb, bf16* __restrict__ h,
    const bf16* __restrict__ wfrag,
    const float* __restrict__ b0, const float* __restrict__ b1,
    const float* __restrict__ inv_s)
{
    __shared__ char lds_raw[4][2048];
    int t = threadIdx.x;
    int w = t >> 6, lane = t & 63;
    int g = lane >> 4, q = lane & 15;
    char* myLds = lds_raw[w];

    bf16x8 wf[2][4][2];
#pragma unroll
    for (int L = 0; L < 2; L++)
#pragma unroll
        for (int nt = 0; nt < 4; nt++)
#pragma unroll
            for (int c = 0; c < 2; c++)
                wf[L][nt][c] = *(const bf16x8*)&wfrag[((((L * 4 + nt) * 2 + c) * 64) + lane) * 8];

    float bias0[4], bias1[4];
#pragma unroll
    for (int nt = 0; nt < 4; nt++) {
        bias0[nt] = b0[nt * 16 + q];
        bias1[nt] = b1[nt * 16 + q];
    }

    const int NTILES = N_NODES / 16;  // 6250
    for (int tile = blockIdx.x * 4 + w; tile < NTILES; tile += gridDim.x * 4) {
        int nodeBase = tile * 16;

        bf16x8 a0[2];
#pragma unroll
        for (int c = 0; c < 2; c++)
            a0[c] = *(const bf16x8*)&xb[(size_t)(nodeBase + q) * 64 + c * 32 + g * 8];

        f32x4 acc[4];
#pragma unroll
        for (int nt = 0; nt < 4; nt++) {
            acc[nt] = (f32x4){bias0[nt], bias0[nt], bias0[nt], bias0[nt]};
            acc[nt] = __builtin_amdgcn_mfma_f32_16x16x32_bf16(a0[0], wf[0][nt][0], acc[nt], 0, 0, 0);
            acc[nt] = __builtin_amdgcn_mfma_f32_16x16x32_bf16(a0[1], wf[0][nt][1], acc[nt], 0, 0, 0);
        }
#pragma unroll
        for (int nt = 0; nt < 4; nt++)
#pragma unroll
            for (int r = 0; r < 4; r++) {
                float v = fmaxf(acc[nt][r], 0.f);
                int node = g * 4 + r;
                int byte = ((node * 128 + (nt * 16 + q) * 2)) ^ ((node & 7) << 4);
                *(bf16*)(myLds + byte) = __float2bfloat16(v);
            }
        bf16x8 a1[2];
#pragma unroll
        for (int c = 0; c < 2; c++) {
            int byte = (q * 128 + c * 64 + g * 16) ^ ((q & 7) << 4);
            a1[c] = *(const bf16x8*)(myLds + byte);
        }

        f32x4 acc1[4];
#pragma unroll
        for (int nt = 0; nt < 4; nt++) {
            acc1[nt] = (f32x4){bias1[nt], bias1[nt], bias1[nt], bias1[nt]};
            acc1[nt] = __builtin_amdgcn_mfma_f32_16x16x32_bf16(a1[0], wf[1][nt][0], acc1[nt], 0, 0, 0);
            acc1[nt] = __builtin_amdgcn_mfma_f32_16x16x32_bf16(a1[1], wf[1][nt][1], acc1[nt], 0, 0, 0);
        }
        float is[4];
#pragma unroll
        for (int r = 0; r < 4; r++) is[r] = inv_s[nodeBase + g * 4 + r];
#pragma unroll
        for (int nt = 0; nt < 4; nt++)
#pragma unroll
            for (int r = 0; r < 4; r++) {
                float v = fmaxf(acc1[nt][r], 0.f) * is[r];
                int node = g * 4 + r;
                int byte = ((node * 128 + (nt * 16 + q) * 2)) ^ ((node & 7) << 4);
                *(bf16*)(myLds + byte) = __float2bfloat16(v);
            }
#pragma unroll
        for (int half = 0; half < 2; half++) {
            int byteL = lane * 32 + half * 16;
            int node = byteL >> 7;
            bf16x8 v = *(const bf16x8*)(myLds + (byteL ^ ((node & 7) << 4)));
            *(bf16x8*)&h[(size_t)nodeBase * 64 + lane * 16 + half * 8] = v;
        }
    }
}

// ---------------- gather-aggregate: 2 rows/VMEM + bf16 skip + LayerNorm -------
__global__ __launch_bounds__(256) void agg_ln_kernel(
    const bf16* __restrict__ h, bf16* __restrict__ xb,
    const int* __restrict__ row_ptr, const int* __restrict__ col,
    const float* __restrict__ inv_r,
    const float* __restrict__ ln_scale, const float* __restrict__ ln_bias)
{
    int t = threadIdx.x;
    int lane = t & 63;
    int sub = lane >> 5;          // which edge of the pair this half-wave handles
    int c = lane & 31;            // this lane covers columns 2c, 2c+1
    float2 lnsv = *(const float2*)&ln_scale[2 * c];
    float2 lnbv = *(const float2*)&ln_bias[2 * c];
    int gw = (blockIdx.x * blockDim.x + t) >> 6;
    int nwaves = (gridDim.x * blockDim.x) >> 6;
    for (int i = gw; i < N_NODES; i += nwaves) {
        float a0 = 0.f, a1 = 0.f, b0 = 0.f, b1 = 0.f;
        // self edge (inv_s already folded into h); count once via sub==0
        unsigned int su = *(const unsigned int*)&h[(size_t)i * 64 + 2 * c];
        if (sub == 0) { a0 += blo(su); a1 += bhi(su); }
        int beg = row_ptr[i], end = row_ptr[i + 1];
        int e = beg;
        for (; e + 8 <= end; e += 8) {
            int r0 = col[e + 0 + sub];
            int r1 = col[e + 2 + sub];
            int r2 = col[e + 4 + sub];
            int r3 = col[e + 6 + sub];
            unsigned int u0 = *(const unsigned int*)&h[(size_t)r0 * 64 + 2 * c];
            unsigned int u1 = *(const unsigned int*)&h[(size_t)r1 * 64 + 2 * c];
            unsigned int u2 = *(const unsigned int*)&h[(size_t)r2 * 64 + 2 * c];
            unsigned int u3 = *(const unsigned int*)&h[(size_t)r3 * 64 + 2 * c];
            a0 += blo(u0) + blo(u1);
            a1 += bhi(u0) + bhi(u1);
            b0 += blo(u2) + blo(u3);
            b1 += bhi(u2) + bhi(u3);
        }
        for (; e < end; e += 2) {
            int idx = e + sub;
            if (idx < end) {
                int r = col[idx];
                unsigned int u = *(const unsigned int*)&h[(size_t)r * 64 + 2 * c];
                a0 += blo(u); a1 += bhi(u);
            }
        }
        a0 += b0; a1 += b1;
        // merge the two half-wave partial sums
        a0 += __shfl_xor(a0, 32);
        a1 += __shfl_xor(a1, 32);
        float ir = inv_r[i];
        unsigned int xu = *(const unsigned int*)&xb[(size_t)i * 64 + 2 * c];
        float y0 = a0 * ir + blo(xu);
        float y1 = a1 * ir + bhi(xu);
        // LayerNorm over 64 cols = 2 per lane x 32 lanes (duplicated across halves)
        float sum = y0 + y1;
#pragma unroll
        for (int m = 1; m < 32; m <<= 1) sum += __shfl_xor(sum, m);
        float mu = sum * (1.f / 64.f);
        float d0 = y0 - mu, d1 = y1 - mu;
        float vs = d0 * d0 + d1 * d1;
#pragma unroll
        for (int m = 1; m < 32; m <<= 1) vs += __shfl_xor(vs, m);
        float var = vs * (1.f / 64.f);
        float rr = rsqrtf(var + 1e-6f);
        float o0 = d0 * rr * lnsv.x + lnbv.x;
        float o1 = d1 * rr * lnsv.y + lnbv.y;
        if (sub == 0) {
            union { unsigned int u; bf16 h2[2]; } pk;
            pk.h2[0] = __float2bfloat16(o0);
            pk.h2[1] = __float2bfloat16(o1);
            *(unsigned int*)&xb[(size_t)i * 64 + 2 * c] = pk.u;
        }
    }
}

// ---------------- pool stage 1: partial sums, vectorized bf16x8 loads ---------
__global__ __launch_bounds__(256) void pool_stage1(
    const bf16* __restrict__ xb, const int* __restrict__ n_node,
    float* __restrict__ partialP)   // [N_GRAPH][POOL_PB][64]
{
    __shared__ float red[32][8][8];  // [row-group][col-chunk][8 cols] = 8 KB
    int b = blockIdx.x;
    int g = b >> 3, sub = b & 7;
    int t = threadIdx.x;
    int start = 0;
    for (int j = 0; j < g; j++) start += n_node[j];
    int cnt = n_node[g];
    int jbeg = (int)(((long long)cnt * sub) / POOL_PB);
    int jend = (int)(((long long)cnt * (sub + 1)) / POOL_PB);
    int rg = t >> 3, cc = t & 7;
    float acc[8];
#pragma unroll
    for (int k = 0; k < 8; k++) acc[k] = 0.f;
    for (int j = jbeg + rg; j < jend; j += 32) {
        bf16x8 v = *(const bf16x8*)&xb[(size_t)(start + j) * 64 + cc * 8];
#pragma unroll
        for (int k = 0; k < 8; k++) acc[k] += bf2f(v[k]);
    }
#pragma unroll
    for (int k = 0; k < 8; k++) red[rg][cc][k] = acc[k];
    __syncthreads();
    if (t < 64) {
        float s = 0.f;
#pragma unroll 8
        for (int r = 0; r < 32; r++) s += red[r][t >> 3][t & 7];
        partialP[((size_t)g * POOL_PB + sub) * 64 + t] = s;
    }
}

// ---------------- pool stage 2: reduce partials + mean + decoder GEMV ---------
__global__ __launch_bounds__(64) void pool_stage2(
    const float* __restrict__ partialP, const int* __restrict__ n_node,
    const float* __restrict__ Wg, const float* __restrict__ bg,
    float* __restrict__ out)
{
    __shared__ float pd[64];
    int g = blockIdx.x;
    int t = threadIdx.x;
    float s = 0.f;
#pragma unroll
    for (int p = 0; p < POOL_PB; p++) s += partialP[((size_t)g * POOL_PB + p) * 64 + t];
    int cnt = n_node[g];
    pd[t] = s / fmaxf((float)cnt, 1.f);
    __syncthreads();
    if (t < OUT_G) {
        float v = bg[t];
#pragma unroll 16
        for (int dd = 0; dd < 64; dd++) v += pd[dd] * Wg[dd * OUT_G + t];
        out[g * OUT_G + t] = v;
    }
}

extern "C" void kernel_launch(void* const* d_in, const int* in_sizes, int n_in,
                              void* d_out, int out_size, void* d_ws, size_t ws_size,
                              hipStream_t stream) {
    const float* nodes    = (const float*)d_in[0];
    const int*   senders  = (const int*)d_in[1];
    const int*   receivers= (const int*)d_in[2];
    const int*   n_node   = (const int*)d_in[3];
    const float* W_embed  = (const float*)d_in[4];
    const float* b_embed  = (const float*)d_in[5];
    const float* W_mlp0   = (const float*)d_in[6];
    const float* b_mlp0   = (const float*)d_in[7];
    const float* W_mlp1   = (const float*)d_in[8];
    const float* b_mlp1   = (const float*)d_in[9];
    const float* ln_scale = (const float*)d_in[10];
    const float* ln_bias  = (const float*)d_in[11];
    const float* W_glob   = (const float*)d_in[12];
    const float* b_glob   = (const float*)d_in[13];
    float* out = (float*)d_out;

    // workspace layout (16B-aligned pieces)
    char* ws = (char*)d_ws;
    bf16*  xb     = (bf16*)ws;    ws += (size_t)N_NODES * 64 * 2;   // 12.8 MB
    bf16*  h      = (bf16*)ws;    ws += (size_t)N_NODES * 64 * 2;   // 12.8 MB
    unsigned int* histS_g = (unsigned int*)ws; ws += (size_t)NSLICE * NCHUNK * CHUNKW * 4; // 12.8 MB
    float* inv_s  = (float*)ws;   ws += (size_t)N_NODES * 4;
    float* inv_r  = (float*)ws;   ws += (size_t)N_NODES * 4;
    int*   cnt_r  = (int*)ws;     ws += (size_t)N_NODES * 4;
    int*   row_ptr= (int*)ws;     ws += (size_t)(N_NODES + 4) * 4;
    int*   col    = (int*)ws;     ws += (size_t)N_EDGES * 4;
    int*   partial= (int*)ws;     ws += 256 * 4;
    bf16*  wfrag  = (bf16*)ws;    ws += 8192 * 2;
    float* partialP = (float*)ws; ws += (size_t)N_GRAPH * POOL_PB * 64 * 4;  // 205 KB

    // CSR-build temporaries alias h/xb (dead until the step loop)
    unsigned int*   histR_g   = (unsigned int*)h;     // 12.8 MB, read before mlp writes h
    unsigned short* blockoffR = (unsigned short*)xb;  // 12.8 MB, read before embed writes xb

    const int nblk_scan = (N_NODES + 1023) / 1024;  // 98

    // ---- CSR build (no global atomics) ----
    csr_hist1<<<NSLICE * NCHUNK, 512, 0, stream>>>(receivers, histR_g);
    csr_hist1<<<NSLICE * NCHUNK, 512, 0, stream>>>(senders, histS_g);
    csr_scan_blocks<<<(NCHUNK * CHUNKW + 255) / 256, 256, 0, stream>>>(
        histR_g, histS_g, blockoffR, cnt_r, inv_r, inv_s);
    scan_blocksum<<<nblk_scan, 256, 0, stream>>>(cnt_r, partial);
    scan_partials_par<<<1, 128, 0, stream>>>(partial, nblk_scan);
    scan_final<<<nblk_scan, 256, 0, stream>>>(cnt_r, partial, row_ptr);
    csr_scatter<<<NSLICE * NCHUNK, 512, 0, stream>>>(senders, receivers, row_ptr, blockoffR, col);

    // ---- embed (after CSR temporaries are dead) ----
    embed_kernel<<<(N_NODES * 8 + 255) / 256, 256, 0, stream>>>(nodes, W_embed, b_embed, xb);
    wfrag_kernel<<<32, 256, 0, stream>>>(W_mlp0, W_mlp1, wfrag);

    for (int step = 0; step < N_STEPS; ++step) {
        mlp_mfma<<<1024, 256, 0, stream>>>(xb, h, wfrag, b_mlp0, b_mlp1, inv_s);
        agg_ln_kernel<<<2048, 256, 0, stream>>>(h, xb, row_ptr, col, inv_r, ln_scale, ln_bias);
    }

    pool_stage1<<<N_GRAPH * POOL_PB, 256, 0, stream>>>(xb, n_node, partialP);
    pool_stage2<<<N_GRAPH, 64, 0, stream>>>(partialP, n_node, W_glob, b_glob, out);
}